// Round 7
// baseline (535.076 us; speedup 1.0000x reference)
//
#include <hip/hip_runtime.h>
#include <math.h>

#define B_SZ 8
#define Hh 64
#define Ww 64
#define L 4096
#define Dm 96
#define Din 192
#define Kd 4
#define Ns 16
#define CPROJ 38
#define ROWW 40           // padded permuted row: [B16|C16|dt6|pad2]
#define NCHUNK 128
#define CHUNK 32

__device__ __forceinline__ float siluf_(float x){ return x / (1.f + __expf(-x)); }

// ---------------- prep: transpose weights ----------------
__global__ void prep_kernel(const float* __restrict__ inw,    // (384,96)
                            const float* __restrict__ xpw,    // (4,38,192)
                            const float* __restrict__ outw,   // (96,192)
                            float* __restrict__ wt_in,        // (96,384)
                            float* __restrict__ wt_x,         // (192,152)
                            float* __restrict__ wt_out){      // (192,96)
  int i = blockIdx.x * blockDim.x + threadIdx.x;
  if (i < Dm*2*Din){ int k = i/(2*Din); int o = i%(2*Din); wt_in[i] = inw[o*Dm + k]; }
  int j = i - Dm*2*Din;
  if (j >= 0 && j < Din*Kd*CPROJ){ int k = j/(Kd*CPROJ); int c = j%(Kd*CPROJ); wt_x[j] = xpw[c*Din + k]; }
  int l = j - Din*Kd*CPROJ;
  if (l >= 0 && l < Din*Dm){ int dd = l/Dm; int o = l%Dm; wt_out[l] = outw[o*Din + dd]; }
}

// ---------------- generic tiled GEMM: C(128p x 128o tile) = X(p,K) @ W(K,O) ----------------
template<int KDIM, int OREAL, int EPI>
__global__ __launch_bounds__(256) void gemm_kernel(const float* __restrict__ X,
    const float* __restrict__ W, float* __restrict__ out0, float* __restrict__ out1){
  __shared__ float4 xt[128*24];    // 48 KB
  const int tid = threadIdx.x;
  const int pg = tid & 15, og = tid >> 4;
  const int pblk = blockIdx.x & 255;
  const int oblk = blockIdx.x >> 8;
  const int p0 = pblk * 128;
  const bool act = (oblk*128 + og*8) < OREAL;   // early-out for padded o-columns
  int oc = oblk*128 + og*8;
  if (oc > OREAL-8) oc = OREAL-8;
  const int sw = pg & 7;

  float acc[8][8];
  #pragma unroll
  for (int i=0;i<8;i++){
    #pragma unroll
    for (int j2=0;j2<8;j2++) acc[i][j2] = 0.f;
  }

  for (int kp = 0; kp < KDIM/96; ++kp){
    __syncthreads();
    for (int idx = tid; idx < 128*24; idx += 256){
      int pp = idx/24, k4 = idx%24;
      size_t prow;
      if (EPI == 1){
        int b = pblk >> 5, tau = pblk & 31;
        int h = ((tau>>2)<<3) + (pp>>4);
        int w = ((tau&3)<<4) + (pp&15);
        prow = (size_t)b*L + h*64 + w;
      } else prow = (size_t)p0 + pp;
      float4 v = *(const float4*)&X[prow*KDIM + (size_t)kp*96 + k4*4];
      xt[pp*24 + (k4 ^ (pp&7))] = v;
    }
    __syncthreads();

    if (act){
      for (int k4 = 0; k4 < 24; ++k4){
        float4 wv[8];
        #pragma unroll
        for (int kk=0;kk<4;kk++){
          const float* wr = &W[(size_t)(kp*96 + k4*4 + kk)*OREAL + oc];
          wv[kk*2]   = *(const float4*)wr;
          wv[kk*2+1] = *(const float4*)(wr+4);
        }
        float4 xv[8];
        #pragma unroll
        for (int i=0;i<8;i++) xv[i] = xt[(pg+16*i)*24 + (k4 ^ sw)];
        #pragma unroll
        for (int kk=0;kk<4;kk++){
          const float4 wa = wv[kk*2], wb = wv[kk*2+1];
          #pragma unroll
          for (int i=0;i<8;i++){
            const float xk = ((const float*)&xv[i])[kk];
            acc[i][0] += xk*wa.x; acc[i][1] += xk*wa.y; acc[i][2] += xk*wa.z; acc[i][3] += xk*wa.w;
            acc[i][4] += xk*wb.x; acc[i][5] += xk*wb.y; acc[i][6] += xk*wb.z; acc[i][7] += xk*wb.w;
          }
        }
      }
    }
  }

  if (!act) return;
  if (EPI == 0){
    #pragma unroll
    for (int i=0;i<8;i++){
      size_t p = (size_t)p0 + pg + 16*i;
      if (oc < Din){
        *(float4*)&out0[p*Din + oc]     = make_float4(acc[i][0],acc[i][1],acc[i][2],acc[i][3]);
        *(float4*)&out0[p*Din + oc + 4] = make_float4(acc[i][4],acc[i][5],acc[i][6],acc[i][7]);
      } else {
        int zo = oc - Din;
        *(float4*)&out1[p*Din + zo]     = make_float4(siluf_(acc[i][0]),siluf_(acc[i][1]),siluf_(acc[i][2]),siluf_(acc[i][3]));
        *(float4*)&out1[p*Din + zo + 4] = make_float4(siluf_(acc[i][4]),siluf_(acc[i][5]),siluf_(acc[i][6]),siluf_(acc[i][7]));
      }
    }
  } else if (EPI == 1){
    const int b = pblk >> 5, tau = pblk & 31;
    #pragma unroll
    for (int i=0;i<8;i++){
      int q = pg + 16*i;
      int h = ((tau>>2)<<3) + (q>>4);
      int w = ((tau&3)<<4) + (q&15);
      int hw = h*64 + w;
      int t1 = ((hw&63)<<6) | (hw>>6);
      #pragma unroll
      for (int j2=0;j2<8;j2++){
        int c = oc + j2;
        int kd = c / CPROJ; int cc = c - kd*CPROJ;
        int t = (kd==0)? hw : (kd==1)? t1 : (kd==2)? (L-1-hw) : (L-1-t1);
        int dcol = (cc < 6) ? (32+cc) : (cc-6);
        out0[((size_t)(b*Kd+kd)*L + t)*ROWW + dcol] = acc[i][j2];
      }
    }
  } else {
    #pragma unroll
    for (int i=0;i<8;i++){
      size_t p = (size_t)p0 + pg + 16*i;
      *(float4*)&out0[p*Dm + oc]     = make_float4(acc[i][0],acc[i][1],acc[i][2],acc[i][3]);
      *(float4*)&out0[p*Dm + oc + 4] = make_float4(acc[i][4],acc[i][5],acc[i][6],acc[i][7]);
    }
  }
}

// ---------------- depthwise 3x3 conv + bias + silu ----------------
__global__ __launch_bounds__(256) void conv_kernel(const float* __restrict__ xp,
    const float* __restrict__ cw, const float* __restrict__ cb, float* __restrict__ u){
  const int gid = blockIdx.x * 256 + threadIdx.x;
  const int d = gid % Din; const int p = gid / Din;
  const int b = p / L; const int hw = p % L; const int h = hw >> 6; const int w = hw & 63;
  float acc = cb[d];
  #pragma unroll
  for (int i=-1;i<=1;i++){
    const int hh = h + i; if (hh < 0 || hh >= Hh) continue;
    #pragma unroll
    for (int j=-1;j<=1;j++){
      const int ww = w + j; if (ww < 0 || ww >= Ww) continue;
      acc += xp[((size_t)(b*L + hh*Ww + ww))*Din + d] * cw[d*9 + (i+1)*3 + (j+1)];
    }
  }
  u[(size_t)p*Din + d] = siluf_(acc);
}

// u position of direction k's timestep t
__device__ __forceinline__ int pos_of(int k, int t){
  if (k == 0) return t;
  if (k == 1) return ((t & 63) << 6) | (t >> 6);
  if (k == 2) return L-1-t;
  const int tp = L-1-t; return ((tp & 63) << 6) | (tp >> 6);
}

// power ladder: e[n] = e1^(n+1), tree-shaped (depth 4)
__device__ __forceinline__ void ladder_(float e1, float* e){
  e[0]=e1;
  #pragma unroll
  for (int n=1;n<16;n++){ int P=n+1; e[n] = e[(P+1)/2 - 1] * e[P/2 - 1]; }
}

// one recurrence step shared by both passes. Returns delta.
__device__ __forceinline__ float scan_step(const float* __restrict__ row, float uval,
    const float* __restrict__ wdt, float bias, const float* __restrict__ a2,
    bool fast, float* __restrict__ hst){
  float dr = bias;
  #pragma unroll
  for (int r=0;r<6;r++) dr += row[32+r]*wdt[r];
  const float p = __expf(dr);
  const float delta = (dr > 20.f) ? dr : __logf(1.f + p);
  const float du = delta * uval;
  float e[16];
  if (fast){
    ladder_(1.f/(1.f + p), e);   // exp(-softplus(dr)) == 1/(1+e^dr)
  } else {
    #pragma unroll
    for (int n=0;n<16;n++) e[n] = __expf(delta * a2[n]);
  }
  #pragma unroll
  for (int n=0;n<16;n++) hst[n] = e[n]*hst[n] + du*row[n];
  return delta;
}

__device__ __forceinline__ float ydot_(const float* __restrict__ hst,
    const float* __restrict__ row){
  float ya=0.f,yb=0.f,yc=0.f,yd=0.f;
  #pragma unroll
  for (int n=0;n<16;n+=4){
    ya += hst[n]*row[16+n];   yb += hst[n+1]*row[17+n];
    yc += hst[n+2]*row[18+n]; yd += hst[n+3]*row[19+n];
  }
  return (ya+yb)+(yc+yd);
}

// ---------------- scan pass 1: TWO chunks per block (ILP), -> q, S ----------------
__global__ __launch_bounds__(192) void scanq_kernel(const float* __restrict__ u,
    const float* __restrict__ xq, const float* __restrict__ dtw,
    const float* __restrict__ dtb, const float* __restrict__ alog,
    float* __restrict__ qout, float* __restrict__ Sout){
  const int bid = blockIdx.x;
  const int cc = bid & 63; const int k = (bid >> 6) & 3; const int b = bid >> 8;
  const int c0 = 2*cc;              // chunks c0, c0+1
  const int d = threadIdx.x;
  const int bk = b*Kd + k;
  float wdt[6];
  #pragma unroll
  for (int r=0;r<6;r++) wdt[r] = dtw[(k*Din + d)*6 + r];
  const float bias = dtb[k*Din + d];
  float a2[16]; bool fastb = true;
  #pragma unroll
  for (int n=0;n<16;n++){
    a2[n] = -__expf(alog[(k*Din + d)*16 + n]);
    fastb = fastb && (fabsf(a2[n] + (float)(n+1)) < 1e-5f*(float)(n+1));
  }
  const bool fast = (bool)__all((int)fastb);
  float h0[16], h1[16];
  #pragma unroll
  for (int n=0;n<16;n++){ h0[n] = 0.f; h1[n] = 0.f; }
  float S0 = 0.f, S1 = 0.f;
  const int tA = c0 * CHUNK;
  const float* __restrict__ urow = u + (size_t)b*L*Din + d;
  const float* __restrict__ rowA = xq + ((size_t)bk*L + tA)*ROWW;
  for (int s = 0; s < CHUNK; ++s){
    const int gpA = pos_of(k, tA + s);
    const int gpB = pos_of(k, tA + CHUNK + s);
    const float uA = urow[(size_t)gpA*Din];
    const float uB = urow[(size_t)gpB*Din];
    S0 += scan_step(rowA + (size_t)s*ROWW,          uA, wdt, bias, a2, fast, h0);
    S1 += scan_step(rowA + (size_t)(CHUNK+s)*ROWW,  uB, wdt, bias, a2, fast, h1);
  }
  const size_t b0 = ((size_t)bk*NCHUNK + c0)*Ns*Din + d;
  #pragma unroll
  for (int n=0;n<16;n++){
    qout[b0 + (size_t)n*Din] = h0[n];
    qout[b0 + (size_t)(Ns+n)*Din] = h1[n];    // chunk c0+1 block is Ns*Din later
  }
  Sout[((size_t)bk*NCHUNK + c0)*Din + d] = S0;
  Sout[((size_t)bk*NCHUNK + c0+1)*Din + d] = S1;
}

// ---------------- combine: sequential over chunks, h_in written in-place over q ----------------
__global__ __launch_bounds__(256) void combine_kernel(const float* __restrict__ alog,
    float* __restrict__ q, const float* __restrict__ Sin){
  const int gid = blockIdx.x * 256 + threadIdx.x;
  if (gid >= B_SZ*Kd*Ns*Din) return;
  const int d = gid % Din; const int n = (gid / Din) % Ns; const int bk = gid / (Din*Ns);
  const int k = bk & 3;
  const float A = -__expf(alog[(k*Din + d)*16 + n]);
  float h = 0.f;
  for (int c=0;c<NCHUNK;c++){
    const size_t idx = (((size_t)bk*NCHUNK + c)*Ns + n)*Din + d;
    const float qv = q[idx];
    q[idx] = h;
    h = __expf(A * Sin[((size_t)bk*NCHUNK + c)*Din + d]) * h + qv;
  }
}

// ---------------- scan pass 2: TWO chunks per block (ILP), atomic merge into ym ----------------
__global__ __launch_bounds__(192) void scany_kernel(const float* __restrict__ u,
    const float* __restrict__ xq, const float* __restrict__ dtw,
    const float* __restrict__ dtb, const float* __restrict__ alog,
    const float* __restrict__ Dsin, const float* __restrict__ hin,
    float* __restrict__ ym){
  const int bid = blockIdx.x;
  const int cc = bid & 63; const int k = (bid >> 6) & 3; const int b = bid >> 8;
  const int c0 = 2*cc;
  const int d = threadIdx.x;
  const int bk = b*Kd + k;

  float wdt[6];
  #pragma unroll
  for (int r=0;r<6;r++) wdt[r] = dtw[(k*Din + d)*6 + r];
  const float bias = dtb[k*Din + d];
  const float Dval = Dsin[k*Din + d];
  float a2[16]; bool fastb = true;
  #pragma unroll
  for (int n=0;n<16;n++){
    a2[n] = -__expf(alog[(k*Din + d)*16 + n]);
    fastb = fastb && (fabsf(a2[n] + (float)(n+1)) < 1e-5f*(float)(n+1));
  }
  const bool fast = (bool)__all((int)fastb);
  float h0[16], h1[16];
  const size_t hb = ((size_t)bk*NCHUNK + c0)*Ns*Din + d;
  #pragma unroll
  for (int n=0;n<16;n++){
    h0[n] = hin[hb + (size_t)n*Din];
    h1[n] = hin[hb + (size_t)(Ns+n)*Din];
  }

  const int tA = c0 * CHUNK;
  const float* __restrict__ urow = u + (size_t)b*L*Din + d;
  float* __restrict__ yrow = ym + (size_t)b*L*Din + d;
  const float* __restrict__ rowA = xq + ((size_t)bk*L + tA)*ROWW;
  for (int s = 0; s < CHUNK; ++s){
    const int gpA = pos_of(k, tA + s);
    const int gpB = pos_of(k, tA + CHUNK + s);
    const float uA = urow[(size_t)gpA*Din];
    const float uB = urow[(size_t)gpB*Din];
    const float* rA = rowA + (size_t)s*ROWW;
    const float* rB = rowA + (size_t)(CHUNK+s)*ROWW;
    float dA = scan_step(rA, uA, wdt, bias, a2, fast, h0);
    float dB = scan_step(rB, uB, wdt, bias, a2, fast, h1);
    (void)dA; (void)dB;
    atomicAdd(&yrow[(size_t)gpA*Din], ydot_(h0, rA) + Dval*uA);
    atomicAdd(&yrow[(size_t)gpB*Din], ydot_(h1, rB) + Dval*uB);
  }
}

// ---------------- LN + gate (ym already merged) ----------------
__global__ __launch_bounds__(192) void lnz_kernel(const float* __restrict__ ym,
    const float* __restrict__ z,
    const float* __restrict__ gw, const float* __restrict__ gb,
    float* __restrict__ yg){
  __shared__ float red[2][4];
  const int p = blockIdx.x;
  const int d = threadIdx.x;
  const size_t i = (size_t)p*Din + d;
  const float yv = ym[i];
  float s = yv, ss = yv*yv;
  #pragma unroll
  for (int off=32; off>=1; off>>=1){ s += __shfl_down(s, off); ss += __shfl_down(ss, off); }
  const int wave = d >> 6;
  if ((d & 63) == 0){ red[0][wave] = s; red[1][wave] = ss; }
  __syncthreads();
  const float mu = (red[0][0]+red[0][1]+red[0][2]) * (1.f/Din);
  const float var = (red[1][0]+red[1][1]+red[1][2]) * (1.f/Din) - mu*mu;
  const float inv = rsqrtf(var + 1e-5f);
  yg[i] = ((yv - mu)*inv*gw[d] + gb[d]) * z[i];
}

extern "C" void kernel_launch(void* const* d_in, const int* in_sizes, int n_in,
                              void* d_out, int out_size, void* d_ws, size_t ws_size,
                              hipStream_t stream) {
  const float* x      = (const float*)d_in[0];
  const float* inw    = (const float*)d_in[1];
  const float* convw  = (const float*)d_in[2];
  const float* convb  = (const float*)d_in[3];
  const float* xprojw = (const float*)d_in[4];
  const float* dtw    = (const float*)d_in[5];
  const float* dtb    = (const float*)d_in[6];
  const float* alog   = (const float*)d_in[7];
  const float* Ds     = (const float*)d_in[8];
  const float* gw     = (const float*)d_in[9];
  const float* gb     = (const float*)d_in[10];
  const float* outw   = (const float*)d_in[11];
  float* out = (float*)d_out;

  float* ws = (float*)d_ws;
  const size_t nBLD  = (size_t)B_SZ*L*Din;
  const size_t nXQ   = (size_t)B_SZ*Kd*L*ROWW;
  const size_t nQ    = (size_t)B_SZ*Kd*NCHUNK*Ns*Din;
  const size_t nS    = (size_t)B_SZ*Kd*NCHUNK*Din;
  size_t off = 0;
  float* xpart = ws + off; off += nBLD;
  float* zbuf  = ws + off; off += nBLD;
  float* ubuf  = ws + off; off += nBLD;
  float* xq    = ws + off; off += nXQ;
  float* qbuf  = ws + off; off += nQ;     // h_in in-place; reused as yg after scany
  float* Sbuf  = ws + off; off += nS;
  float* ym    = ws + off; off += nBLD;
  float* wt_in = ws + off; off += (size_t)Dm*2*Din;
  float* wt_x  = ws + off; off += (size_t)Din*Kd*CPROJ;
  float* wt_out= ws + off; off += (size_t)Din*Dm;

  hipMemsetAsync(ym, 0, nBLD*sizeof(float), stream);

  const int prepN = Dm*2*Din + Din*Kd*CPROJ + Din*Dm;
  prep_kernel<<<(prepN + 255)/256, 256, 0, stream>>>(inw, xprojw, outw, wt_in, wt_x, wt_out);
  gemm_kernel<Dm, 2*Din, 0><<<256*3, 256, 0, stream>>>(x, wt_in, xpart, zbuf);
  conv_kernel<<<(int)(nBLD/256), 256, 0, stream>>>(xpart, convw, convb, ubuf);
  gemm_kernel<Din, Kd*CPROJ, 1><<<256*2, 256, 0, stream>>>(ubuf, wt_x, xq, nullptr);
  scanq_kernel<<<B_SZ*Kd*NCHUNK/2, Din, 0, stream>>>(ubuf, xq, dtw, dtb, alog, qbuf, Sbuf);
  combine_kernel<<<(B_SZ*Kd*Ns*Din + 255)/256, 256, 0, stream>>>(alog, qbuf, Sbuf);
  scany_kernel<<<B_SZ*Kd*NCHUNK/2, Din, 0, stream>>>(ubuf, xq, dtw, dtb, alog, Ds, qbuf, ym);
  lnz_kernel<<<B_SZ*L, Din, 0, stream>>>(ym, zbuf, gw, gb, qbuf);
  gemm_kernel<Din, Dm, 2><<<256*1, 256, 0, stream>>>(qbuf, wt_out, out, nullptr);
}

// Round 8
// 501.419 us; speedup vs baseline: 1.0671x; 1.0671x over previous
//
#include <hip/hip_runtime.h>
#include <math.h>

#define B_SZ 8
#define Hh 64
#define Ww 64
#define L 4096
#define Dm 96
#define Din 192
#define Kd 4
#define Ns 16
#define CPROJ 38
#define ROWW 40           // padded permuted row: [B16|C16|dt6|pad2]
#define NCHUNK 128
#define CHUNK 32

__device__ __forceinline__ float siluf_(float x){ return x / (1.f + __expf(-x)); }

// ---------------- prep: transpose weights ----------------
__global__ void prep_kernel(const float* __restrict__ inw,    // (384,96)
                            const float* __restrict__ xpw,    // (4,38,192)
                            const float* __restrict__ outw,   // (96,192)
                            float* __restrict__ wt_in,        // (96,384)
                            float* __restrict__ wt_x,         // (192,152)
                            float* __restrict__ wt_out){      // (192,96)
  int i = blockIdx.x * blockDim.x + threadIdx.x;
  if (i < Dm*2*Din){ int k = i/(2*Din); int o = i%(2*Din); wt_in[i] = inw[o*Dm + k]; }
  int j = i - Dm*2*Din;
  if (j >= 0 && j < Din*Kd*CPROJ){ int k = j/(Kd*CPROJ); int c = j%(Kd*CPROJ); wt_x[j] = xpw[c*Din + k]; }
  int l = j - Din*Kd*CPROJ;
  if (l >= 0 && l < Din*Dm){ int dd = l/Dm; int o = l%Dm; wt_out[l] = outw[o*Din + dd]; }
}

// ---------------- zero-fill (replaces hipMemsetAsync; guaranteed fast path) ----------------
__global__ __launch_bounds__(256) void zero_kernel(float4* __restrict__ p, int n4){
  int i = blockIdx.x * 256 + threadIdx.x;
  if (i < n4) p[i] = make_float4(0.f,0.f,0.f,0.f);
}

// ---------------- generic tiled GEMM: C(128p x 128o tile) = X(p,K) @ W(K,O) ----------------
template<int KDIM, int OREAL, int EPI>
__global__ __launch_bounds__(256) void gemm_kernel(const float* __restrict__ X,
    const float* __restrict__ W, float* __restrict__ out0, float* __restrict__ out1){
  __shared__ float4 xt[128*24];    // 48 KB
  const int tid = threadIdx.x;
  const int pg = tid & 15, og = tid >> 4;
  const int pblk = blockIdx.x & 255;
  const int oblk = blockIdx.x >> 8;
  const int p0 = pblk * 128;
  const bool act = (oblk*128 + og*8) < OREAL;   // early-out for padded o-columns
  int oc = oblk*128 + og*8;
  if (oc > OREAL-8) oc = OREAL-8;
  const int sw = pg & 7;

  float acc[8][8];
  #pragma unroll
  for (int i=0;i<8;i++){
    #pragma unroll
    for (int j2=0;j2<8;j2++) acc[i][j2] = 0.f;
  }

  for (int kp = 0; kp < KDIM/96; ++kp){
    __syncthreads();
    for (int idx = tid; idx < 128*24; idx += 256){
      int pp = idx/24, k4 = idx%24;
      size_t prow;
      if (EPI == 1){
        int b = pblk >> 5, tau = pblk & 31;
        int h = ((tau>>2)<<3) + (pp>>4);
        int w = ((tau&3)<<4) + (pp&15);
        prow = (size_t)b*L + h*64 + w;
      } else prow = (size_t)p0 + pp;
      float4 v = *(const float4*)&X[prow*KDIM + (size_t)kp*96 + k4*4];
      xt[pp*24 + (k4 ^ (pp&7))] = v;
    }
    __syncthreads();

    if (act){
      for (int k4 = 0; k4 < 24; ++k4){
        float4 wv[8];
        #pragma unroll
        for (int kk=0;kk<4;kk++){
          const float* wr = &W[(size_t)(kp*96 + k4*4 + kk)*OREAL + oc];
          wv[kk*2]   = *(const float4*)wr;
          wv[kk*2+1] = *(const float4*)(wr+4);
        }
        float4 xv[8];
        #pragma unroll
        for (int i=0;i<8;i++) xv[i] = xt[(pg+16*i)*24 + (k4 ^ sw)];
        #pragma unroll
        for (int kk=0;kk<4;kk++){
          const float4 wa = wv[kk*2], wb = wv[kk*2+1];
          #pragma unroll
          for (int i=0;i<8;i++){
            const float xk = ((const float*)&xv[i])[kk];
            acc[i][0] += xk*wa.x; acc[i][1] += xk*wa.y; acc[i][2] += xk*wa.z; acc[i][3] += xk*wa.w;
            acc[i][4] += xk*wb.x; acc[i][5] += xk*wb.y; acc[i][6] += xk*wb.z; acc[i][7] += xk*wb.w;
          }
        }
      }
    }
  }

  if (!act) return;
  if (EPI == 0){
    #pragma unroll
    for (int i=0;i<8;i++){
      size_t p = (size_t)p0 + pg + 16*i;
      if (oc < Din){
        *(float4*)&out0[p*Din + oc]     = make_float4(acc[i][0],acc[i][1],acc[i][2],acc[i][3]);
        *(float4*)&out0[p*Din + oc + 4] = make_float4(acc[i][4],acc[i][5],acc[i][6],acc[i][7]);
      } else {
        int zo = oc - Din;
        *(float4*)&out1[p*Din + zo]     = make_float4(siluf_(acc[i][0]),siluf_(acc[i][1]),siluf_(acc[i][2]),siluf_(acc[i][3]));
        *(float4*)&out1[p*Din + zo + 4] = make_float4(siluf_(acc[i][4]),siluf_(acc[i][5]),siluf_(acc[i][6]),siluf_(acc[i][7]));
      }
    }
  } else if (EPI == 1){
    const int b = pblk >> 5, tau = pblk & 31;
    #pragma unroll
    for (int i=0;i<8;i++){
      int q = pg + 16*i;
      int h = ((tau>>2)<<3) + (q>>4);
      int w = ((tau&3)<<4) + (q&15);
      int hw = h*64 + w;
      int t1 = ((hw&63)<<6) | (hw>>6);
      #pragma unroll
      for (int j2=0;j2<8;j2++){
        int c = oc + j2;
        int kd = c / CPROJ; int cc = c - kd*CPROJ;
        int t = (kd==0)? hw : (kd==1)? t1 : (kd==2)? (L-1-hw) : (L-1-t1);
        int dcol = (cc < 6) ? (32+cc) : (cc-6);
        out0[((size_t)(b*Kd+kd)*L + t)*ROWW + dcol] = acc[i][j2];
      }
    }
  } else {
    #pragma unroll
    for (int i=0;i<8;i++){
      size_t p = (size_t)p0 + pg + 16*i;
      *(float4*)&out0[p*Dm + oc]     = make_float4(acc[i][0],acc[i][1],acc[i][2],acc[i][3]);
      *(float4*)&out0[p*Dm + oc + 4] = make_float4(acc[i][4],acc[i][5],acc[i][6],acc[i][7]);
    }
  }
}

// ---------------- depthwise 3x3 conv + bias + silu ----------------
__global__ __launch_bounds__(256) void conv_kernel(const float* __restrict__ xp,
    const float* __restrict__ cw, const float* __restrict__ cb, float* __restrict__ u){
  const int gid = blockIdx.x * 256 + threadIdx.x;
  const int d = gid % Din; const int p = gid / Din;
  const int b = p / L; const int hw = p % L; const int h = hw >> 6; const int w = hw & 63;
  float acc = cb[d];
  #pragma unroll
  for (int i=-1;i<=1;i++){
    const int hh = h + i; if (hh < 0 || hh >= Hh) continue;
    #pragma unroll
    for (int j=-1;j<=1;j++){
      const int ww = w + j; if (ww < 0 || ww >= Ww) continue;
      acc += xp[((size_t)(b*L + hh*Ww + ww))*Din + d] * cw[d*9 + (i+1)*3 + (j+1)];
    }
  }
  u[(size_t)p*Din + d] = siluf_(acc);
}

// affine u-position within a chunk: pos_of(k, t0+s) = gp0 + s*gstr  (valid for CHUNK<=32, t0%32==0)
__device__ __forceinline__ void affine_pos(int k, int t0, int& gp0, int& gstr){
  if (k == 0){ gp0 = t0; gstr = 1; }
  else if (k == 1){ gp0 = ((t0 & 63) << 6) | (t0 >> 6); gstr = 64; }
  else if (k == 2){ gp0 = L-1-t0; gstr = -1; }
  else { const int T0 = L-1-t0; gp0 = ((T0 & 63) << 6) | (T0 >> 6); gstr = -64; }
}

// power ladder: e[n] = e1^(n+1), tree-shaped (depth 4)
__device__ __forceinline__ void ladder_(float e1, float* e){
  e[0]=e1;
  #pragma unroll
  for (int n=1;n<16;n++){ int P=n+1; e[n] = e[(P+1)/2 - 1] * e[P/2 - 1]; }
}

// one recurrence step shared by both passes. Returns delta.
__device__ __forceinline__ float scan_step(const float* __restrict__ row, float uval,
    const float* __restrict__ wdt, float bias, const float* __restrict__ a2,
    bool fast, float* __restrict__ hst){
  float dr = bias;
  #pragma unroll
  for (int r=0;r<6;r++) dr += row[32+r]*wdt[r];
  const float p = __expf(dr);
  const float delta = (dr > 20.f) ? dr : __logf(1.f + p);
  const float du = delta * uval;
  float e[16];
  if (fast){
    ladder_(1.f/(1.f + p), e);   // exp(-softplus(dr)) == 1/(1+e^dr)
  } else {
    #pragma unroll
    for (int n=0;n<16;n++) e[n] = __expf(delta * a2[n]);
  }
  #pragma unroll
  for (int n=0;n<16;n++) hst[n] = e[n]*hst[n] + du*row[n];
  return delta;
}

__device__ __forceinline__ float ydot_(const float* __restrict__ hst,
    const float* __restrict__ row){
  float ya=0.f,yb=0.f,yc=0.f,yd=0.f;
  #pragma unroll
  for (int n=0;n<16;n+=4){
    ya += hst[n]*row[16+n];   yb += hst[n+1]*row[17+n];
    yc += hst[n+2]*row[18+n]; yd += hst[n+3]*row[19+n];
  }
  return (ya+yb)+(yc+yd);
}

// ---------------- scan pass 1: per-chunk local scan -> q (zero-init end state), S (sum delta) ----------------
__global__ __launch_bounds__(192) void scanq_kernel(const float* __restrict__ u,
    const float* __restrict__ xq, const float* __restrict__ dtw,
    const float* __restrict__ dtb, const float* __restrict__ alog,
    float* __restrict__ qout, float* __restrict__ Sout){
  const int bid = blockIdx.x;
  const int c = bid & (NCHUNK-1); const int k = (bid >> 7) & 3; const int b = bid >> 9;
  const int d = threadIdx.x;
  const int bk = b*Kd + k;
  float wdt[6];
  #pragma unroll
  for (int r=0;r<6;r++) wdt[r] = dtw[(k*Din + d)*6 + r];
  const float bias = dtb[k*Din + d];
  float a2[16]; bool fastb = true;
  #pragma unroll
  for (int n=0;n<16;n++){
    a2[n] = -__expf(alog[(k*Din + d)*16 + n]);
    fastb = fastb && (fabsf(a2[n] + (float)(n+1)) < 1e-5f*(float)(n+1));
  }
  const bool fast = (bool)__all((int)fastb);
  float hst[16];
  #pragma unroll
  for (int n=0;n<16;n++) hst[n] = 0.f;
  float S = 0.f;
  const int t0 = c * CHUNK;
  int gp0, gstr; affine_pos(k, t0, gp0, gstr);
  const float* __restrict__ up = u + (size_t)b*L*Din + (size_t)gp0*Din + d;
  const ptrdiff_t ustep = (ptrdiff_t)gstr * Din;
  const float* __restrict__ rowp = xq + ((size_t)bk*L + t0)*ROWW;
  for (int s = 0; s < CHUNK; ++s){
    S += scan_step(rowp, *up, wdt, bias, a2, fast, hst);
    up += ustep; rowp += ROWW;
  }
  const size_t base = ((size_t)bk*NCHUNK + c)*Ns*Din + d;
  #pragma unroll
  for (int n=0;n<16;n++) qout[base + (size_t)n*Din] = hst[n];
  Sout[((size_t)bk*NCHUNK + c)*Din + d] = S;
}

// ---------------- combine: sequential over chunks, h_in written in-place over q ----------------
__global__ __launch_bounds__(256) void combine_kernel(const float* __restrict__ alog,
    float* __restrict__ q, const float* __restrict__ Sin){
  const int gid = blockIdx.x * 256 + threadIdx.x;
  if (gid >= B_SZ*Kd*Ns*Din) return;
  const int d = gid % Din; const int n = (gid / Din) % Ns; const int bk = gid / (Din*Ns);
  const int k = bk & 3;
  const float A = -__expf(alog[(k*Din + d)*16 + n]);
  float h = 0.f;
  for (int c=0;c<NCHUNK;c++){
    const size_t idx = (((size_t)bk*NCHUNK + c)*Ns + n)*Din + d;
    const float qv = q[idx];
    q[idx] = h;
    h = __expf(A * Sin[((size_t)bk*NCHUNK + c)*Din + d]) * h + qv;
  }
}

// ---------------- scan pass 2: one chain per block, affine addressing, atomic merge into ym ----------------
__global__ __launch_bounds__(192) void scany_kernel(const float* __restrict__ u,
    const float* __restrict__ xq, const float* __restrict__ dtw,
    const float* __restrict__ dtb, const float* __restrict__ alog,
    const float* __restrict__ Dsin, const float* __restrict__ hin,
    float* __restrict__ ym){
  const int bid = blockIdx.x;
  const int c = bid & (NCHUNK-1); const int k = (bid >> 7) & 3; const int b = bid >> 9;
  const int d = threadIdx.x;
  const int bk = b*Kd + k;

  float wdt[6];
  #pragma unroll
  for (int r=0;r<6;r++) wdt[r] = dtw[(k*Din + d)*6 + r];
  const float bias = dtb[k*Din + d];
  const float Dval = Dsin[k*Din + d];
  float a2[16]; bool fastb = true;
  #pragma unroll
  for (int n=0;n<16;n++){
    a2[n] = -__expf(alog[(k*Din + d)*16 + n]);
    fastb = fastb && (fabsf(a2[n] + (float)(n+1)) < 1e-5f*(float)(n+1));
  }
  const bool fast = (bool)__all((int)fastb);
  float hst[16];
  const size_t hbase = ((size_t)bk*NCHUNK + c)*Ns*Din + d;
  #pragma unroll
  for (int n=0;n<16;n++) hst[n] = hin[hbase + (size_t)n*Din];

  const int t0 = c * CHUNK;
  int gp0, gstr; affine_pos(k, t0, gp0, gstr);
  const float* __restrict__ up = u + (size_t)b*L*Din + (size_t)gp0*Din + d;
  float* __restrict__ yp = ym + (size_t)b*L*Din + (size_t)gp0*Din + d;
  const ptrdiff_t ustep = (ptrdiff_t)gstr * Din;
  const float* __restrict__ rowp = xq + ((size_t)bk*L + t0)*ROWW;
  for (int s = 0; s < CHUNK; ++s){
    const float uval = *up;
    scan_step(rowp, uval, wdt, bias, a2, fast, hst);
    atomicAdd(yp, ydot_(hst, rowp) + Dval*uval);
    up += ustep; yp += ustep; rowp += ROWW;
  }
}

// ---------------- LN + gate (ym already merged) ----------------
__global__ __launch_bounds__(192) void lnz_kernel(const float* __restrict__ ym,
    const float* __restrict__ z,
    const float* __restrict__ gw, const float* __restrict__ gb,
    float* __restrict__ yg){
  __shared__ float red[2][4];
  const int p = blockIdx.x;
  const int d = threadIdx.x;
  const size_t i = (size_t)p*Din + d;
  const float yv = ym[i];
  float s = yv, ss = yv*yv;
  #pragma unroll
  for (int off=32; off>=1; off>>=1){ s += __shfl_down(s, off); ss += __shfl_down(ss, off); }
  const int wave = d >> 6;
  if ((d & 63) == 0){ red[0][wave] = s; red[1][wave] = ss; }
  __syncthreads();
  const float mu = (red[0][0]+red[0][1]+red[0][2]) * (1.f/Din);
  const float var = (red[1][0]+red[1][1]+red[1][2]) * (1.f/Din) - mu*mu;
  const float inv = rsqrtf(var + 1e-5f);
  yg[i] = ((yv - mu)*inv*gw[d] + gb[d]) * z[i];
}

extern "C" void kernel_launch(void* const* d_in, const int* in_sizes, int n_in,
                              void* d_out, int out_size, void* d_ws, size_t ws_size,
                              hipStream_t stream) {
  const float* x      = (const float*)d_in[0];
  const float* inw    = (const float*)d_in[1];
  const float* convw  = (const float*)d_in[2];
  const float* convb  = (const float*)d_in[3];
  const float* xprojw = (const float*)d_in[4];
  const float* dtw    = (const float*)d_in[5];
  const float* dtb    = (const float*)d_in[6];
  const float* alog   = (const float*)d_in[7];
  const float* Ds     = (const float*)d_in[8];
  const float* gw     = (const float*)d_in[9];
  const float* gb     = (const float*)d_in[10];
  const float* outw   = (const float*)d_in[11];
  float* out = (float*)d_out;

  float* ws = (float*)d_ws;
  const size_t nBLD  = (size_t)B_SZ*L*Din;
  const size_t nXQ   = (size_t)B_SZ*Kd*L*ROWW;
  const size_t nQ    = (size_t)B_SZ*Kd*NCHUNK*Ns*Din;
  const size_t nS    = (size_t)B_SZ*Kd*NCHUNK*Din;
  size_t off = 0;
  float* xpart = ws + off; off += nBLD;
  float* zbuf  = ws + off; off += nBLD;
  float* ubuf  = ws + off; off += nBLD;
  float* xq    = ws + off; off += nXQ;
  float* qbuf  = ws + off; off += nQ;     // h_in in-place; reused as yg after scany
  float* Sbuf  = ws + off; off += nS;
  float* ym    = ws + off; off += nBLD;
  float* wt_in = ws + off; off += (size_t)Dm*2*Din;
  float* wt_x  = ws + off; off += (size_t)Din*Kd*CPROJ;
  float* wt_out= ws + off; off += (size_t)Din*Dm;

  const int prepN = Dm*2*Din + Din*Kd*CPROJ + Din*Dm;
  prep_kernel<<<(prepN + 255)/256, 256, 0, stream>>>(inw, xprojw, outw, wt_in, wt_x, wt_out);
  zero_kernel<<<(int)(nBLD/4 + 255)/256, 256, 0, stream>>>((float4*)ym, (int)(nBLD/4));
  gemm_kernel<Dm, 2*Din, 0><<<256*3, 256, 0, stream>>>(x, wt_in, xpart, zbuf);
  conv_kernel<<<(int)(nBLD/256), 256, 0, stream>>>(xpart, convw, convb, ubuf);
  gemm_kernel<Din, Kd*CPROJ, 1><<<256*2, 256, 0, stream>>>(ubuf, wt_x, xq, nullptr);
  scanq_kernel<<<B_SZ*Kd*NCHUNK, Din, 0, stream>>>(ubuf, xq, dtw, dtb, alog, qbuf, Sbuf);
  combine_kernel<<<(B_SZ*Kd*Ns*Din + 255)/256, 256, 0, stream>>>(alog, qbuf, Sbuf);
  scany_kernel<<<B_SZ*Kd*NCHUNK, Din, 0, stream>>>(ubuf, xq, dtw, dtb, alog, Ds, qbuf, ym);
  lnz_kernel<<<B_SZ*L, Din, 0, stream>>>(ym, zbuf, gw, gb, qbuf);
  gemm_kernel<Din, Dm, 2><<<256*1, 256, 0, stream>>>(qbuf, wt_out, out, nullptr);
}

// Round 9
// 470.926 us; speedup vs baseline: 1.1362x; 1.0648x over previous
//
#include <hip/hip_runtime.h>
#include <math.h>

#define B_SZ 8
#define Hh 64
#define Ww 64
#define L 4096
#define Dm 96
#define Din 192
#define Kd 4
#define Ns 16
#define CPROJ 38
#define ROWW 40           // padded permuted row: [B16|C16|dt6|pad2]
#define NCHUNK 128
#define CHUNK 32

__device__ __forceinline__ float siluf_(float x){ return x / (1.f + __expf(-x)); }

// ---------------- prep: transpose weights ----------------
__global__ void prep_kernel(const float* __restrict__ inw,    // (384,96)
                            const float* __restrict__ xpw,    // (4,38,192)
                            const float* __restrict__ outw,   // (96,192)
                            float* __restrict__ wt_in,        // (96,384)
                            float* __restrict__ wt_x,         // (192,152)
                            float* __restrict__ wt_out){      // (192,96)
  int i = blockIdx.x * blockDim.x + threadIdx.x;
  if (i < Dm*2*Din){ int k = i/(2*Din); int o = i%(2*Din); wt_in[i] = inw[o*Dm + k]; }
  int j = i - Dm*2*Din;
  if (j >= 0 && j < Din*Kd*CPROJ){ int k = j/(Kd*CPROJ); int c = j%(Kd*CPROJ); wt_x[j] = xpw[c*Din + k]; }
  int l = j - Din*Kd*CPROJ;
  if (l >= 0 && l < Din*Dm){ int dd = l/Dm; int o = l%Dm; wt_out[l] = outw[o*Din + dd]; }
}

// ---------------- zero-fill ----------------
__global__ __launch_bounds__(256) void zero_kernel(float4* __restrict__ p, int n4){
  int i = blockIdx.x * 256 + threadIdx.x;
  if (i < n4) p[i] = make_float4(0.f,0.f,0.f,0.f);
}

// ---------------- generic tiled GEMM: C(128p x 128o tile) = X(p,K) @ W(K,O) ----------------
template<int KDIM, int OREAL, int EPI>
__global__ __launch_bounds__(256) void gemm_kernel(const float* __restrict__ X,
    const float* __restrict__ W, float* __restrict__ out0, float* __restrict__ out1){
  __shared__ float4 xt[128*24];    // 48 KB
  const int tid = threadIdx.x;
  const int pg = tid & 15, og = tid >> 4;
  const int pblk = blockIdx.x & 255;
  const int oblk = blockIdx.x >> 8;
  const int p0 = pblk * 128;
  const bool act = (oblk*128 + og*8) < OREAL;
  int oc = oblk*128 + og*8;
  if (oc > OREAL-8) oc = OREAL-8;
  const int sw = pg & 7;

  float acc[8][8];
  #pragma unroll
  for (int i=0;i<8;i++){
    #pragma unroll
    for (int j2=0;j2<8;j2++) acc[i][j2] = 0.f;
  }

  for (int kp = 0; kp < KDIM/96; ++kp){
    __syncthreads();
    for (int idx = tid; idx < 128*24; idx += 256){
      int pp = idx/24, k4 = idx%24;
      size_t prow;
      if (EPI == 1){
        int b = pblk >> 5, tau = pblk & 31;
        int h = ((tau>>2)<<3) + (pp>>4);
        int w = ((tau&3)<<4) + (pp&15);
        prow = (size_t)b*L + h*64 + w;
      } else prow = (size_t)p0 + pp;
      float4 v = *(const float4*)&X[prow*KDIM + (size_t)kp*96 + k4*4];
      xt[pp*24 + (k4 ^ (pp&7))] = v;
    }
    __syncthreads();

    if (act){
      for (int k4 = 0; k4 < 24; ++k4){
        float4 wv[8];
        #pragma unroll
        for (int kk=0;kk<4;kk++){
          const float* wr = &W[(size_t)(kp*96 + k4*4 + kk)*OREAL + oc];
          wv[kk*2]   = *(const float4*)wr;
          wv[kk*2+1] = *(const float4*)(wr+4);
        }
        float4 xv[8];
        #pragma unroll
        for (int i=0;i<8;i++) xv[i] = xt[(pg+16*i)*24 + (k4 ^ sw)];
        #pragma unroll
        for (int kk=0;kk<4;kk++){
          const float4 wa = wv[kk*2], wb = wv[kk*2+1];
          #pragma unroll
          for (int i=0;i<8;i++){
            const float xk = ((const float*)&xv[i])[kk];
            acc[i][0] += xk*wa.x; acc[i][1] += xk*wa.y; acc[i][2] += xk*wa.z; acc[i][3] += xk*wa.w;
            acc[i][4] += xk*wb.x; acc[i][5] += xk*wb.y; acc[i][6] += xk*wb.z; acc[i][7] += xk*wb.w;
          }
        }
      }
    }
  }

  if (!act) return;
  if (EPI == 0){
    #pragma unroll
    for (int i=0;i<8;i++){
      size_t p = (size_t)p0 + pg + 16*i;
      if (oc < Din){
        *(float4*)&out0[p*Din + oc]     = make_float4(acc[i][0],acc[i][1],acc[i][2],acc[i][3]);
        *(float4*)&out0[p*Din + oc + 4] = make_float4(acc[i][4],acc[i][5],acc[i][6],acc[i][7]);
      } else {
        int zo = oc - Din;
        *(float4*)&out1[p*Din + zo]     = make_float4(siluf_(acc[i][0]),siluf_(acc[i][1]),siluf_(acc[i][2]),siluf_(acc[i][3]));
        *(float4*)&out1[p*Din + zo + 4] = make_float4(siluf_(acc[i][4]),siluf_(acc[i][5]),siluf_(acc[i][6]),siluf_(acc[i][7]));
      }
    }
  } else {   // EPI == 1
    const int b = pblk >> 5, tau = pblk & 31;
    #pragma unroll
    for (int i=0;i<8;i++){
      int q = pg + 16*i;
      int h = ((tau>>2)<<3) + (q>>4);
      int w = ((tau&3)<<4) + (q&15);
      int hw = h*64 + w;
      int t1 = ((hw&63)<<6) | (hw>>6);
      #pragma unroll
      for (int j2=0;j2<8;j2++){
        int c = oc + j2;
        int kd = c / CPROJ; int cc = c - kd*CPROJ;
        int t = (kd==0)? hw : (kd==1)? t1 : (kd==2)? (L-1-hw) : (L-1-t1);
        int dcol = (cc < 6) ? (32+cc) : (cc-6);
        out0[((size_t)(b*Kd+kd)*L + t)*ROWW + dcol] = acc[i][j2];
      }
    }
  }
}

// ---------------- depthwise 3x3 conv + bias + silu ----------------
__global__ __launch_bounds__(256) void conv_kernel(const float* __restrict__ xp,
    const float* __restrict__ cw, const float* __restrict__ cb, float* __restrict__ u){
  const int gid = blockIdx.x * 256 + threadIdx.x;
  const int d = gid % Din; const int p = gid / Din;
  const int b = p / L; const int hw = p % L; const int h = hw >> 6; const int w = hw & 63;
  float acc = cb[d];
  #pragma unroll
  for (int i=-1;i<=1;i++){
    const int hh = h + i; if (hh < 0 || hh >= Hh) continue;
    #pragma unroll
    for (int j=-1;j<=1;j++){
      const int ww = w + j; if (ww < 0 || ww >= Ww) continue;
      acc += xp[((size_t)(b*L + hh*Ww + ww))*Din + d] * cw[d*9 + (i+1)*3 + (j+1)];
    }
  }
  u[(size_t)p*Din + d] = siluf_(acc);
}

// affine u-position within a chunk: pos_of(k, t0+s) = gp0 + s*gstr (CHUNK<=32, t0%32==0)
__device__ __forceinline__ void affine_pos(int k, int t0, int& gp0, int& gstr){
  if (k == 0){ gp0 = t0; gstr = 1; }
  else if (k == 1){ gp0 = ((t0 & 63) << 6) | (t0 >> 6); gstr = 64; }
  else if (k == 2){ gp0 = L-1-t0; gstr = -1; }
  else { const int T0 = L-1-t0; gp0 = ((T0 & 63) << 6) | (T0 >> 6); gstr = -64; }
}

// power ladder: e[n] = e1^(n+1), tree-shaped (depth 4)
__device__ __forceinline__ void ladder_(float e1, float* e){
  e[0]=e1;
  #pragma unroll
  for (int n=1;n<16;n++){ int P=n+1; e[n] = e[(P+1)/2 - 1] * e[P/2 - 1]; }
}

// ---------------- scan pass 1: per-chunk local scan -> q, S ----------------
__global__ __launch_bounds__(192) void scanq_kernel(const float* __restrict__ u,
    const float* __restrict__ xq, const float* __restrict__ dtw,
    const float* __restrict__ dtb, const float* __restrict__ alog,
    float* __restrict__ qout, float* __restrict__ Sout){
  const int bid = blockIdx.x;
  const int c = bid & (NCHUNK-1); const int k = (bid >> 7) & 3; const int b = bid >> 9;
  const int d = threadIdx.x;
  const int bk = b*Kd + k;
  float wdt[6];
  #pragma unroll
  for (int r=0;r<6;r++) wdt[r] = dtw[(k*Din + d)*6 + r];
  const float bias = dtb[k*Din + d];
  float a2[16]; bool fastb = true;
  #pragma unroll
  for (int n=0;n<16;n++){
    a2[n] = -__expf(alog[(k*Din + d)*16 + n]);
    fastb = fastb && (fabsf(a2[n] + (float)(n+1)) < 1e-5f*(float)(n+1));
  }
  const bool fast = (bool)__all((int)fastb);
  float h[16];
  #pragma unroll
  for (int n=0;n<16;n++) h[n] = 0.f;
  float S = 0.f;
  const int t0 = c * CHUNK;
  int gp0, gstr; affine_pos(k, t0, gp0, gstr);
  const float* __restrict__ up = u + (size_t)b*L*Din + (size_t)gp0*Din + d;
  const ptrdiff_t ustep = (ptrdiff_t)gstr * Din;
  const float* __restrict__ rowp = xq + ((size_t)bk*L + t0)*ROWW;
  #pragma unroll 4
  for (int s = 0; s < CHUNK; ++s){
    const float4* __restrict__ rq = (const float4*)rowp;
    const float4 B0=rq[0],B1=rq[1],B2=rq[2],B3=rq[3];
    const float4 D0=rq[8];
    const float2 D1=((const float2*)rowp)[18];
    const float uval = *up;
    float dr = bias + D0.x*wdt[0]+D0.y*wdt[1]+D0.z*wdt[2]+D0.w*wdt[3]+D1.x*wdt[4]+D1.y*wdt[5];
    const float pp = __expf(dr);
    const float delta = (dr > 20.f) ? dr : __logf(1.f + pp);
    S += delta;
    const float du = delta * uval;
    float e[16];
    if (fast){
      ladder_(__builtin_amdgcn_rcpf(1.f + pp), e);   // exp(-softplus) = 1/(1+e^dr)
    } else {
      #pragma unroll
      for (int n=0;n<16;n++) e[n] = __expf(delta * a2[n]);
    }
    h[0] =e[0] *h[0] +du*B0.x; h[1] =e[1] *h[1] +du*B0.y; h[2] =e[2] *h[2] +du*B0.z; h[3] =e[3] *h[3] +du*B0.w;
    h[4] =e[4] *h[4] +du*B1.x; h[5] =e[5] *h[5] +du*B1.y; h[6] =e[6] *h[6] +du*B1.z; h[7] =e[7] *h[7] +du*B1.w;
    h[8] =e[8] *h[8] +du*B2.x; h[9] =e[9] *h[9] +du*B2.y; h[10]=e[10]*h[10]+du*B2.z; h[11]=e[11]*h[11]+du*B2.w;
    h[12]=e[12]*h[12]+du*B3.x; h[13]=e[13]*h[13]+du*B3.y; h[14]=e[14]*h[14]+du*B3.z; h[15]=e[15]*h[15]+du*B3.w;
    up += ustep; rowp += ROWW;
  }
  const size_t base = ((size_t)bk*NCHUNK + c)*Ns*Din + d;
  #pragma unroll
  for (int n=0;n<16;n++) qout[base + (size_t)n*Din] = h[n];
  Sout[((size_t)bk*NCHUNK + c)*Din + d] = S;
}

// ---------------- combine: sequential over chunks, separate in/out (no alias) ----------------
__global__ __launch_bounds__(256) void combine_kernel(const float* __restrict__ alog,
    const float* __restrict__ qin, const float* __restrict__ Sin, float* __restrict__ hout){
  const int gid = blockIdx.x * 256 + threadIdx.x;
  if (gid >= B_SZ*Kd*Ns*Din) return;
  const int d = gid % Din; const int n = (gid / Din) % Ns; const int bk = gid / (Din*Ns);
  const int k = bk & 3;
  const float A = -__expf(alog[(k*Din + d)*16 + n]);
  float h = 0.f;
  #pragma unroll 2
  for (int c=0;c<NCHUNK;c++){
    const size_t idx = (((size_t)bk*NCHUNK + c)*Ns + n)*Din + d;
    hout[idx] = h;
    h = __expf(A * Sin[((size_t)bk*NCHUNK + c)*Din + d]) * h + qin[idx];
  }
}

// ---------------- scan pass 2: affine addressing, float4 rows, atomic merge into ym ----------------
__global__ __launch_bounds__(192) void scany_kernel(const float* __restrict__ u,
    const float* __restrict__ xq, const float* __restrict__ dtw,
    const float* __restrict__ dtb, const float* __restrict__ alog,
    const float* __restrict__ Dsin, const float* __restrict__ hin,
    float* __restrict__ ym){
  const int bid = blockIdx.x;
  const int c = bid & (NCHUNK-1); const int k = (bid >> 7) & 3; const int b = bid >> 9;
  const int d = threadIdx.x;
  const int bk = b*Kd + k;

  float wdt[6];
  #pragma unroll
  for (int r=0;r<6;r++) wdt[r] = dtw[(k*Din + d)*6 + r];
  const float bias = dtb[k*Din + d];
  const float Dval = Dsin[k*Din + d];
  float a2[16]; bool fastb = true;
  #pragma unroll
  for (int n=0;n<16;n++){
    a2[n] = -__expf(alog[(k*Din + d)*16 + n]);
    fastb = fastb && (fabsf(a2[n] + (float)(n+1)) < 1e-5f*(float)(n+1));
  }
  const bool fast = (bool)__all((int)fastb);
  float h[16];
  const size_t hbase = ((size_t)bk*NCHUNK + c)*Ns*Din + d;
  #pragma unroll
  for (int n=0;n<16;n++) h[n] = hin[hbase + (size_t)n*Din];

  const int t0 = c * CHUNK;
  int gp0, gstr; affine_pos(k, t0, gp0, gstr);
  const float* __restrict__ up = u + (size_t)b*L*Din + (size_t)gp0*Din + d;
  float* __restrict__ yp = ym + (size_t)b*L*Din + (size_t)gp0*Din + d;
  const ptrdiff_t ustep = (ptrdiff_t)gstr * Din;
  const float* __restrict__ rowp = xq + ((size_t)bk*L + t0)*ROWW;
  #pragma unroll 4
  for (int s = 0; s < CHUNK; ++s){
    const float4* __restrict__ rq = (const float4*)rowp;
    const float4 B0=rq[0],B1=rq[1],B2=rq[2],B3=rq[3];
    const float4 C0=rq[4],C1=rq[5],C2=rq[6],C3=rq[7];
    const float4 D0=rq[8];
    const float2 D1=((const float2*)rowp)[18];
    const float uval = *up;
    float dr = bias + D0.x*wdt[0]+D0.y*wdt[1]+D0.z*wdt[2]+D0.w*wdt[3]+D1.x*wdt[4]+D1.y*wdt[5];
    const float pp = __expf(dr);
    const float delta = (dr > 20.f) ? dr : __logf(1.f + pp);
    const float du = delta * uval;
    float e[16];
    if (fast){
      ladder_(__builtin_amdgcn_rcpf(1.f + pp), e);
    } else {
      #pragma unroll
      for (int n=0;n<16;n++) e[n] = __expf(delta * a2[n]);
    }
    h[0] =e[0] *h[0] +du*B0.x; h[1] =e[1] *h[1] +du*B0.y; h[2] =e[2] *h[2] +du*B0.z; h[3] =e[3] *h[3] +du*B0.w;
    h[4] =e[4] *h[4] +du*B1.x; h[5] =e[5] *h[5] +du*B1.y; h[6] =e[6] *h[6] +du*B1.z; h[7] =e[7] *h[7] +du*B1.w;
    h[8] =e[8] *h[8] +du*B2.x; h[9] =e[9] *h[9] +du*B2.z==0.f?h[9]:e[9]*h[9]+du*B2.y; // placeholder guard removed below
    h[9] =e[9] *h[9]; // (see corrected lines below)
    up += ustep; yp += ustep; rowp += ROWW;
  }
}

// NOTE: the above scany body contains an editing error; the real implementation is
// scany_kernel2 below, which is the one actually launched.
__global__ __launch_bounds__(192) void scany_kernel2(const float* __restrict__ u,
    const float* __restrict__ xq, const float* __restrict__ dtw,
    const float* __restrict__ dtb, const float* __restrict__ alog,
    const float* __restrict__ Dsin, const float* __restrict__ hin,
    float* __restrict__ ym){
  const int bid = blockIdx.x;
  const int c = bid & (NCHUNK-1); const int k = (bid >> 7) & 3; const int b = bid >> 9;
  const int d = threadIdx.x;
  const int bk = b*Kd + k;

  float wdt[6];
  #pragma unroll
  for (int r=0;r<6;r++) wdt[r] = dtw[(k*Din + d)*6 + r];
  const float bias = dtb[k*Din + d];
  const float Dval = Dsin[k*Din + d];
  float a2[16]; bool fastb = true;
  #pragma unroll
  for (int n=0;n<16;n++){
    a2[n] = -__expf(alog[(k*Din + d)*16 + n]);
    fastb = fastb && (fabsf(a2[n] + (float)(n+1)) < 1e-5f*(float)(n+1));
  }
  const bool fast = (bool)__all((int)fastb);
  float h[16];
  const size_t hbase = ((size_t)bk*NCHUNK + c)*Ns*Din + d;
  #pragma unroll
  for (int n=0;n<16;n++) h[n] = hin[hbase + (size_t)n*Din];

  const int t0 = c * CHUNK;
  int gp0, gstr; affine_pos(k, t0, gp0, gstr);
  const float* __restrict__ up = u + (size_t)b*L*Din + (size_t)gp0*Din + d;
  float* __restrict__ yp = ym + (size_t)b*L*Din + (size_t)gp0*Din + d;
  const ptrdiff_t ustep = (ptrdiff_t)gstr * Din;
  const float* __restrict__ rowp = xq + ((size_t)bk*L + t0)*ROWW;
  #pragma unroll 4
  for (int s = 0; s < CHUNK; ++s){
    const float4* __restrict__ rq = (const float4*)rowp;
    const float4 B0=rq[0],B1=rq[1],B2=rq[2],B3=rq[3];
    const float4 C0=rq[4],C1=rq[5],C2=rq[6],C3=rq[7];
    const float4 D0=rq[8];
    const float2 D1=((const float2*)rowp)[18];
    const float uval = *up;
    float dr = bias + D0.x*wdt[0]+D0.y*wdt[1]+D0.z*wdt[2]+D0.w*wdt[3]+D1.x*wdt[4]+D1.y*wdt[5];
    const float pp = __expf(dr);
    const float delta = (dr > 20.f) ? dr : __logf(1.f + pp);
    const float du = delta * uval;
    float e[16];
    if (fast){
      ladder_(__builtin_amdgcn_rcpf(1.f + pp), e);
    } else {
      #pragma unroll
      for (int n=0;n<16;n++) e[n] = __expf(delta * a2[n]);
    }
    h[0] =e[0] *h[0] +du*B0.x; h[1] =e[1] *h[1] +du*B0.y; h[2] =e[2] *h[2] +du*B0.z; h[3] =e[3] *h[3] +du*B0.w;
    h[4] =e[4] *h[4] +du*B1.x; h[5] =e[5] *h[5] +du*B1.y; h[6] =e[6] *h[6] +du*B1.z; h[7] =e[7] *h[7] +du*B1.w;
    h[8] =e[8] *h[8] +du*B2.x; h[9] =e[9] *h[9] +du*B2.y; h[10]=e[10]*h[10]+du*B2.z; h[11]=e[11]*h[11]+du*B2.w;
    h[12]=e[12]*h[12]+du*B3.x; h[13]=e[13]*h[13]+du*B3.y; h[14]=e[14]*h[14]+du*B3.z; h[15]=e[15]*h[15]+du*B3.w;
    float y0 = h[0]*C0.x + h[1]*C0.y;  float y1 = h[2]*C0.z + h[3]*C0.w;
    float y2 = h[4]*C1.x + h[5]*C1.y;  float y3 = h[6]*C1.z + h[7]*C1.w;
    y0 += h[8]*C2.x + h[9]*C2.y;   y1 += h[10]*C2.z + h[11]*C2.w;
    y2 += h[12]*C3.x + h[13]*C3.y; y3 += h[14]*C3.z + h[15]*C3.w;
    atomicAdd(yp, (y0+y1)+(y2+y3) + Dval*uval);
    up += ustep; yp += ustep; rowp += ROWW;
  }
}

// ---------------- fused LN + gate + out_proj ----------------
__global__ __launch_bounds__(192) void outproj_kernel(const float* __restrict__ ym,
    const float* __restrict__ z, const float* __restrict__ gw, const float* __restrict__ gb,
    const float* __restrict__ wto,   // (192,96)
    float* __restrict__ out){
  __shared__ float xt[64*192];
  __shared__ float smu[64], sinv[64];
  const int tid = threadIdx.x;
  const int p0 = blockIdx.x * 64;
  // phase A: row stats (2 threads per row)
  if (tid < 128){
    const int r = tid >> 1, part = tid & 1;
    const float4* __restrict__ src = (const float4*)(ym + (size_t)(p0 + r)*Din + part*96);
    float s = 0.f, ss = 0.f;
    #pragma unroll
    for (int i=0;i<24;i++){
      float4 v = src[i];
      s  += (v.x+v.y)+(v.z+v.w);
      ss += (v.x*v.x+v.y*v.y)+(v.z*v.z+v.w*v.w);
    }
    s += __shfl_xor(s, 1); ss += __shfl_xor(ss, 1);
    if (!part){
      const float mu = s * (1.f/Din);
      smu[r] = mu;
      sinv[r] = rsqrtf(ss*(1.f/Din) - mu*mu + 1e-5f);
    }
  }
  __syncthreads();
  // phase B: stage normalized+gated tile (swizzled float4 columns)
  for (int idx = tid; idx < 64*48; idx += 192){
    const int r = idx/48, k4 = idx - (idx/48)*48;
    const size_t g = (size_t)(p0+r)*Din + k4*4;
    float4 v  = *(const float4*)(ym + g);
    const float4 zv = *(const float4*)(z + g);
    const float4 gwv = *(const float4*)(gw + k4*4);
    const float4 gbv = *(const float4*)(gb + k4*4);
    const float mu = smu[r], inv = sinv[r];
    v.x = ((v.x-mu)*inv*gwv.x + gbv.x)*zv.x;
    v.y = ((v.y-mu)*inv*gwv.y + gbv.y)*zv.y;
    v.z = ((v.z-mu)*inv*gwv.z + gbv.z)*zv.z;
    v.w = ((v.w-mu)*inv*gwv.w + gbv.w)*zv.w;
    const int k4s = (k4 & ~7) | ((k4 ^ r) & 7);
    *(float4*)(xt + r*192 + k4s*4) = v;
  }
  __syncthreads();
  // phase C: GEMM 64x96 = xt(64,192) @ wto(192,96)
  const int pg = tid/12, og = tid - (tid/12)*12;   // 16 x 12
  const int oc = og*8;
  float acc[4][8];
  #pragma unroll
  for (int i=0;i<4;i++){
    #pragma unroll
    for (int j=0;j<8;j++) acc[i][j] = 0.f;
  }
  for (int k4 = 0; k4 < 48; ++k4){
    float4 xv[4];
    #pragma unroll
    for (int i=0;i<4;i++){
      const int r = pg*4+i;
      const int k4s = (k4 & ~7) | ((k4 ^ r) & 7);
      xv[i] = *(const float4*)(xt + r*192 + k4s*4);
    }
    #pragma unroll
    for (int j=0;j<4;j++){
      const int k = k4*4 + j;
      const float4 w0 = *(const float4*)(wto + (size_t)k*Dm + oc);
      const float4 w1 = *(const float4*)(wto + (size_t)k*Dm + oc + 4);
      #pragma unroll
      for (int i=0;i<4;i++){
        const float xk = ((const float*)&xv[i])[j];
        acc[i][0] += xk*w0.x; acc[i][1] += xk*w0.y; acc[i][2] += xk*w0.z; acc[i][3] += xk*w0.w;
        acc[i][4] += xk*w1.x; acc[i][5] += xk*w1.y; acc[i][6] += xk*w1.z; acc[i][7] += xk*w1.w;
      }
    }
  }
  #pragma unroll
  for (int i=0;i<4;i++){
    const size_t row = (size_t)p0 + pg*4 + i;
    *(float4*)(out + row*Dm + oc)     = make_float4(acc[i][0],acc[i][1],acc[i][2],acc[i][3]);
    *(float4*)(out + row*Dm + oc + 4) = make_float4(acc[i][4],acc[i][5],acc[i][6],acc[i][7]);
  }
}

extern "C" void kernel_launch(void* const* d_in, const int* in_sizes, int n_in,
                              void* d_out, int out_size, void* d_ws, size_t ws_size,
                              hipStream_t stream) {
  const float* x      = (const float*)d_in[0];
  const float* inw    = (const float*)d_in[1];
  const float* convw  = (const float*)d_in[2];
  const float* convb  = (const float*)d_in[3];
  const float* xprojw = (const float*)d_in[4];
  const float* dtw    = (const float*)d_in[5];
  const float* dtb    = (const float*)d_in[6];
  const float* alog   = (const float*)d_in[7];
  const float* Ds     = (const float*)d_in[8];
  const float* gw     = (const float*)d_in[9];
  const float* gb     = (const float*)d_in[10];
  const float* outw   = (const float*)d_in[11];
  float* out = (float*)d_out;

  float* ws = (float*)d_ws;
  const size_t nBLD  = (size_t)B_SZ*L*Din;
  const size_t nXQ   = (size_t)B_SZ*Kd*L*ROWW;
  const size_t nQ    = (size_t)B_SZ*Kd*NCHUNK*Ns*Din;
  const size_t nS    = (size_t)B_SZ*Kd*NCHUNK*Din;
  size_t off = 0;
  float* xpart = ws + off; off += nQ;     // gemm0 out / conv in; later reused as hin (nQ >= nBLD)
  float* zbuf  = ws + off; off += nBLD;
  float* ubuf  = ws + off; off += nBLD;
  float* xq    = ws + off; off += nXQ;
  float* qbuf  = ws + off; off += nQ;
  float* Sbuf  = ws + off; off += nS;
  float* ym    = ws + off; off += nBLD;
  float* wt_in = ws + off; off += (size_t)Dm*2*Din;
  float* wt_x  = ws + off; off += (size_t)Din*Kd*CPROJ;
  float* wt_out= ws + off; off += (size_t)Din*Dm;

  const int prepN = Dm*2*Din + Din*Kd*CPROJ + Din*Dm;
  prep_kernel<<<(prepN + 255)/256, 256, 0, stream>>>(inw, xprojw, outw, wt_in, wt_x, wt_out);
  zero_kernel<<<(int)(nBLD/4 + 255)/256, 256, 0, stream>>>((float4*)ym, (int)(nBLD/4));
  gemm_kernel<Dm, 2*Din, 0><<<256*3, 256, 0, stream>>>(x, wt_in, xpart, zbuf);
  conv_kernel<<<(int)(nBLD/256), 256, 0, stream>>>(xpart, convw, convb, ubuf);
  gemm_kernel<Din, Kd*CPROJ, 1><<<256*2, 256, 0, stream>>>(ubuf, wt_x, xq, nullptr);
  scanq_kernel<<<B_SZ*Kd*NCHUNK, Din, 0, stream>>>(ubuf, xq, dtw, dtb, alog, qbuf, Sbuf);
  combine_kernel<<<(B_SZ*Kd*Ns*Din + 255)/256, 256, 0, stream>>>(alog, qbuf, Sbuf, xpart);
  scany_kernel2<<<B_SZ*Kd*NCHUNK, Din, 0, stream>>>(ubuf, xq, dtw, dtb, alog, Ds, xpart, ym);
  outproj_kernel<<<B_SZ*L/64, 192, 0, stream>>>(ym, zbuf, gw, gb, wt_out, out);
}

// Round 10
// 455.900 us; speedup vs baseline: 1.1737x; 1.0330x over previous
//
#include <hip/hip_runtime.h>
#include <math.h>

#define B_SZ 8
#define Hh 64
#define Ww 64
#define L 4096
#define Dm 96
#define Din 192
#define Kd 4
#define Ns 16
#define CPROJ 38
#define ROWW 40           // padded permuted row: [B16|C16|dt6|pad2], spatial order (b,k,hw)
#define NCHUNK 128
#define CHUNK 32

__device__ __forceinline__ float siluf_(float x){ return x / (1.f + __expf(-x)); }

// ---------------- prep: transpose weights ----------------
__global__ void prep_kernel(const float* __restrict__ inw,    // (384,96)
                            const float* __restrict__ xpw,    // (4,38,192)
                            const float* __restrict__ outw,   // (96,192)
                            float* __restrict__ wt_in,        // (96,384)
                            float* __restrict__ wt_x,         // (192,152)
                            float* __restrict__ wt_out){      // (192,96)
  int i = blockIdx.x * blockDim.x + threadIdx.x;
  if (i < Dm*2*Din){ int k = i/(2*Din); int o = i%(2*Din); wt_in[i] = inw[o*Dm + k]; }
  int j = i - Dm*2*Din;
  if (j >= 0 && j < Din*Kd*CPROJ){ int k = j/(Kd*CPROJ); int c = j%(Kd*CPROJ); wt_x[j] = xpw[c*Din + k]; }
  int l = j - Din*Kd*CPROJ;
  if (l >= 0 && l < Din*Dm){ int dd = l/Dm; int o = l%Dm; wt_out[l] = outw[o*Din + dd]; }
}

// ---------------- zero-fill ----------------
__global__ __launch_bounds__(256) void zero_kernel(float4* __restrict__ p, int n4){
  int i = blockIdx.x * 256 + threadIdx.x;
  if (i < n4) p[i] = make_float4(0.f,0.f,0.f,0.f);
}

// ---------------- generic tiled GEMM: C(128p x 128o tile) = X(p,K) @ W(K,O) ----------------
// EPI 0: inproj split -> xpart | silu(z).  EPI 1: xdbl spatial store (linear rows, col permute).
template<int KDIM, int OREAL, int EPI>
__global__ __launch_bounds__(256) void gemm_kernel(const float* __restrict__ X,
    const float* __restrict__ W, float* __restrict__ out0, float* __restrict__ out1){
  __shared__ float4 xt[128*24];    // 48 KB
  const int tid = threadIdx.x;
  const int pg = tid & 15, og = tid >> 4;
  const int pblk = blockIdx.x & 255;
  const int oblk = blockIdx.x >> 8;
  const int p0 = pblk * 128;
  const bool act = (oblk*128 + og*8) < OREAL;
  int oc = oblk*128 + og*8;
  if (oc > OREAL-8) oc = OREAL-8;
  const int sw = pg & 7;

  float acc[8][8];
  #pragma unroll
  for (int i=0;i<8;i++){
    #pragma unroll
    for (int j2=0;j2<8;j2++) acc[i][j2] = 0.f;
  }

  for (int kp = 0; kp < KDIM/96; ++kp){
    __syncthreads();
    for (int idx = tid; idx < 128*24; idx += 256){
      int pp = idx/24, k4 = idx%24;
      size_t prow = (size_t)p0 + pp;
      float4 v = *(const float4*)&X[prow*KDIM + (size_t)kp*96 + k4*4];
      xt[pp*24 + (k4 ^ (pp&7))] = v;
    }
    __syncthreads();

    if (act){
      for (int k4 = 0; k4 < 24; ++k4){
        float4 wv[8];
        #pragma unroll
        for (int kk=0;kk<4;kk++){
          const float* wr = &W[(size_t)(kp*96 + k4*4 + kk)*OREAL + oc];
          wv[kk*2]   = *(const float4*)wr;
          wv[kk*2+1] = *(const float4*)(wr+4);
        }
        float4 xv[8];
        #pragma unroll
        for (int i=0;i<8;i++) xv[i] = xt[(pg+16*i)*24 + (k4 ^ sw)];
        #pragma unroll
        for (int kk=0;kk<4;kk++){
          const float4 wa = wv[kk*2], wb = wv[kk*2+1];
          #pragma unroll
          for (int i=0;i<8;i++){
            const float xk = ((const float*)&xv[i])[kk];
            acc[i][0] += xk*wa.x; acc[i][1] += xk*wa.y; acc[i][2] += xk*wa.z; acc[i][3] += xk*wa.w;
            acc[i][4] += xk*wb.x; acc[i][5] += xk*wb.y; acc[i][6] += xk*wb.z; acc[i][7] += xk*wb.w;
          }
        }
      }
    }
  }

  if (!act) return;
  if (EPI == 0){
    #pragma unroll
    for (int i=0;i<8;i++){
      size_t p = (size_t)p0 + pg + 16*i;
      if (oc < Din){
        *(float4*)&out0[p*Din + oc]     = make_float4(acc[i][0],acc[i][1],acc[i][2],acc[i][3]);
        *(float4*)&out0[p*Din + oc + 4] = make_float4(acc[i][4],acc[i][5],acc[i][6],acc[i][7]);
      } else {
        int zo = oc - Din;
        *(float4*)&out1[p*Din + zo]     = make_float4(siluf_(acc[i][0]),siluf_(acc[i][1]),siluf_(acc[i][2]),siluf_(acc[i][3]));
        *(float4*)&out1[p*Din + zo + 4] = make_float4(siluf_(acc[i][4]),siluf_(acc[i][5]),siluf_(acc[i][6]),siluf_(acc[i][7]));
      }
    }
  } else {   // EPI == 1: spatial xq store (linear rows)
    #pragma unroll
    for (int i=0;i<8;i++){
      const int p = p0 + pg + 16*i;
      const int b = p >> 12;          // p / L
      const int hw = p & (L-1);
      #pragma unroll
      for (int j2=0;j2<8;j2++){
        int c = oc + j2;
        int kd = c / CPROJ; int cc = c - kd*CPROJ;
        int dcol = (cc < 6) ? (32+cc) : (cc-6);
        out0[((size_t)(b*Kd+kd)*L + hw)*ROWW + dcol] = acc[i][j2];
      }
    }
  }
}

// ---------------- depthwise 3x3 conv + bias + silu ----------------
__global__ __launch_bounds__(256) void conv_kernel(const float* __restrict__ xp,
    const float* __restrict__ cw, const float* __restrict__ cb, float* __restrict__ u){
  const int gid = blockIdx.x * 256 + threadIdx.x;
  const int d = gid % Din; const int p = gid / Din;
  const int b = p / L; const int hw = p % L; const int h = hw >> 6; const int w = hw & 63;
  float acc = cb[d];
  #pragma unroll
  for (int i=-1;i<=1;i++){
    const int hh = h + i; if (hh < 0 || hh >= Hh) continue;
    #pragma unroll
    for (int j=-1;j<=1;j++){
      const int ww = w + j; if (ww < 0 || ww >= Ww) continue;
      acc += xp[((size_t)(b*L + hh*Ww + ww))*Din + d] * cw[d*9 + (i+1)*3 + (j+1)];
    }
  }
  u[(size_t)p*Din + d] = siluf_(acc);
}

// affine u-position within a chunk: pos_of(k, t0+s) = gp0 + s*gstr (CHUNK<=32, t0%32==0)
__device__ __forceinline__ void affine_pos(int k, int t0, int& gp0, int& gstr){
  if (k == 0){ gp0 = t0; gstr = 1; }
  else if (k == 1){ gp0 = ((t0 & 63) << 6) | (t0 >> 6); gstr = 64; }
  else if (k == 2){ gp0 = L-1-t0; gstr = -1; }
  else { const int T0 = L-1-t0; gp0 = ((T0 & 63) << 6) | (T0 >> 6); gstr = -64; }
}

// power ladder: e[n] = e1^(n+1), tree-shaped (depth 4)
__device__ __forceinline__ void ladder_(float e1, float* e){
  e[0]=e1;
  #pragma unroll
  for (int n=1;n<16;n++){ int P=n+1; e[n] = e[(P+1)/2 - 1] * e[P/2 - 1]; }
}

// ---------------- pass 1: local recurrence (h_in=0) -> y_local into ym, q & S out ----------------
__global__ __launch_bounds__(192) void scan_local_kernel(const float* __restrict__ u,
    const float* __restrict__ xq, const float* __restrict__ dtw,
    const float* __restrict__ dtb, const float* __restrict__ alog,
    const float* __restrict__ Dsin,
    float* __restrict__ qout, float* __restrict__ Sout, float* __restrict__ ym){
  const int bid = blockIdx.x;
  const int c = bid & (NCHUNK-1); const int k = (bid >> 7) & 3; const int b = bid >> 9;
  const int d = threadIdx.x;
  const int bk = b*Kd + k;
  float wdt[6];
  #pragma unroll
  for (int r=0;r<6;r++) wdt[r] = dtw[(k*Din + d)*6 + r];
  const float bias = dtb[k*Din + d];
  const float Dval = Dsin[k*Din + d];
  float a2[16]; bool fastb = true;
  #pragma unroll
  for (int n=0;n<16;n++){
    a2[n] = -__expf(alog[(k*Din + d)*16 + n]);
    fastb = fastb && (fabsf(a2[n] + (float)(n+1)) < 1e-5f*(float)(n+1));
  }
  const bool fast = (bool)__all((int)fastb);
  float h[16];
  #pragma unroll
  for (int n=0;n<16;n++) h[n] = 0.f;
  float S = 0.f;
  const int t0 = c * CHUNK;
  int gp0, gstr; affine_pos(k, t0, gp0, gstr);
  const float* __restrict__ up = u + (size_t)b*L*Din + (size_t)gp0*Din + d;
  float* __restrict__ yp = ym + (size_t)b*L*Din + (size_t)gp0*Din + d;
  const ptrdiff_t ustep = (ptrdiff_t)gstr * Din;
  const float* __restrict__ rowp = xq + ((size_t)bk*L + gp0)*ROWW;
  const ptrdiff_t rstep = (ptrdiff_t)gstr * ROWW;
  #pragma unroll 4
  for (int s = 0; s < CHUNK; ++s){
    const float4* __restrict__ rq = (const float4*)rowp;
    const float4 B0=rq[0],B1=rq[1],B2=rq[2],B3=rq[3];
    const float4 C0=rq[4],C1=rq[5],C2=rq[6],C3=rq[7];
    const float4 D0=rq[8];
    const float2 D1=((const float2*)rowp)[18];
    const float uval = *up;
    float dr = bias + D0.x*wdt[0]+D0.y*wdt[1]+D0.z*wdt[2]+D0.w*wdt[3]+D1.x*wdt[4]+D1.y*wdt[5];
    const float pp = __expf(dr);
    const float delta = (dr > 20.f) ? dr : __logf(1.f + pp);
    S += delta;
    const float du = delta * uval;
    float e[16];
    if (fast){
      ladder_(__builtin_amdgcn_rcpf(1.f + pp), e);   // exp(-softplus) = 1/(1+e^dr)
    } else {
      #pragma unroll
      for (int n=0;n<16;n++) e[n] = __expf(delta * a2[n]);
    }
    h[0] =e[0] *h[0] +du*B0.x; h[1] =e[1] *h[1] +du*B0.y; h[2] =e[2] *h[2] +du*B0.z; h[3] =e[3] *h[3] +du*B0.w;
    h[4] =e[4] *h[4] +du*B1.x; h[5] =e[5] *h[5] +du*B1.y; h[6] =e[6] *h[6] +du*B1.z; h[7] =e[7] *h[7] +du*B1.w;
    h[8] =e[8] *h[8] +du*B2.x; h[9] =e[9] *h[9] +du*B2.y; h[10]=e[10]*h[10]+du*B2.z; h[11]=e[11]*h[11]+du*B2.w;
    h[12]=e[12]*h[12]+du*B3.x; h[13]=e[13]*h[13]+du*B3.y; h[14]=e[14]*h[14]+du*B3.z; h[15]=e[15]*h[15]+du*B3.w;
    float y0 = h[0]*C0.x + h[1]*C0.y;  float y1 = h[2]*C0.z + h[3]*C0.w;
    float y2 = h[4]*C1.x + h[5]*C1.y;  float y3 = h[6]*C1.z + h[7]*C1.w;
    y0 += h[8]*C2.x + h[9]*C2.y;   y1 += h[10]*C2.z + h[11]*C2.w;
    y2 += h[12]*C3.x + h[13]*C3.y; y3 += h[14]*C3.z + h[15]*C3.w;
    atomicAdd(yp, (y0+y1)+(y2+y3) + Dval*uval);
    up += ustep; yp += ustep; rowp += rstep;
  }
  const size_t base = ((size_t)bk*NCHUNK + c)*Ns*Din + d;
  #pragma unroll
  for (int n=0;n<16;n++) qout[base + (size_t)n*Din] = h[n];
  Sout[((size_t)bk*NCHUNK + c)*Din + d] = S;
}

// ---------------- combine: sequential over chunks, batch-8 load-ahead ----------------
__global__ __launch_bounds__(256) void combine_kernel(const float* __restrict__ alog,
    const float* __restrict__ qin, const float* __restrict__ Sin, float* __restrict__ hout){
  const int gid = blockIdx.x * 256 + threadIdx.x;
  if (gid >= B_SZ*Kd*Ns*Din) return;
  const int d = gid % Din; const int n = (gid / Din) % Ns; const int bk = gid / (Din*Ns);
  const int k = bk & 3;
  const float A = -__expf(alog[(k*Din + d)*16 + n]);
  const size_t stepQ = (size_t)Ns*Din;
  size_t idx = ((size_t)bk*NCHUNK)*stepQ + (size_t)n*Din + d;
  size_t sidx = ((size_t)bk*NCHUNK)*Din + d;
  float h = 0.f;
  for (int c0=0;c0<NCHUNK;c0+=8){
    float qv[8], Sv[8];
    #pragma unroll
    for (int j=0;j<8;j++){ qv[j] = qin[idx + (size_t)j*stepQ]; Sv[j] = Sin[sidx + (size_t)j*Din]; }
    #pragma unroll
    for (int j=0;j<8;j++){
      hout[idx + (size_t)j*stepQ] = h;
      h = __expf(A*Sv[j])*h + qv[j];
    }
    idx += 8*stepQ; sidx += (size_t)8*Din;
  }
}

// ---------------- pass 2: correction y += C_t · (E_t^(n+1) ⊙ h_in) ----------------
__global__ __launch_bounds__(192) void scan_corr_kernel(const float* __restrict__ xq,
    const float* __restrict__ dtw, const float* __restrict__ dtb,
    const float* __restrict__ alog, const float* __restrict__ hin,
    float* __restrict__ ym){
  const int bid = blockIdx.x;
  const int c = bid & (NCHUNK-1); const int k = (bid >> 7) & 3; const int b = bid >> 9;
  const int d = threadIdx.x;
  const int bk = b*Kd + k;
  float wdt[6];
  #pragma unroll
  for (int r=0;r<6;r++) wdt[r] = dtw[(k*Din + d)*6 + r];
  const float bias = dtb[k*Din + d];
  float a2[16]; bool fastb = true;
  #pragma unroll
  for (int n=0;n<16;n++){
    a2[n] = -__expf(alog[(k*Din + d)*16 + n]);
    fastb = fastb && (fabsf(a2[n] + (float)(n+1)) < 1e-5f*(float)(n+1));
  }
  const bool fast = (bool)__all((int)fastb);
  float g[16];
  const size_t hbase = ((size_t)bk*NCHUNK + c)*Ns*Din + d;
  #pragma unroll
  for (int n=0;n<16;n++) g[n] = hin[hbase + (size_t)n*Din];

  const int t0 = c * CHUNK;
  int gp0, gstr; affine_pos(k, t0, gp0, gstr);
  float* __restrict__ yp = ym + (size_t)b*L*Din + (size_t)gp0*Din + d;
  const ptrdiff_t ustep = (ptrdiff_t)gstr * Din;
  const float* __restrict__ rowp = xq + ((size_t)bk*L + gp0)*ROWW;
  const ptrdiff_t rstep = (ptrdiff_t)gstr * ROWW;
  float E = 1.f, cumS = 0.f;
  #pragma unroll 4
  for (int s = 0; s < CHUNK; ++s){
    const float4* __restrict__ rq = (const float4*)rowp;
    const float4 C0=rq[4],C1=rq[5],C2=rq[6],C3=rq[7];
    const float4 D0=rq[8];
    const float2 D1=((const float2*)rowp)[18];
    float dr = bias + D0.x*wdt[0]+D0.y*wdt[1]+D0.z*wdt[2]+D0.w*wdt[3]+D1.x*wdt[4]+D1.y*wdt[5];
    const float pp = __expf(dr);
    float lad[16];
    if (fast){
      E *= __builtin_amdgcn_rcpf(1.f + pp);
      ladder_(E, lad);                       // lad[n] = E^(n+1) = exp(A_n * cumS)
    } else {
      const float delta = (dr > 20.f) ? dr : __logf(1.f + pp);
      cumS += delta;
      #pragma unroll
      for (int n=0;n<16;n++) lad[n] = __expf(a2[n]*cumS);
    }
    float w0[16];
    #pragma unroll
    for (int n=0;n<16;n++) w0[n] = lad[n]*g[n];
    float y0 = w0[0]*C0.x + w0[1]*C0.y;  float y1 = w0[2]*C0.z + w0[3]*C0.w;
    float y2 = w0[4]*C1.x + w0[5]*C1.y;  float y3 = w0[6]*C1.z + w0[7]*C1.w;
    y0 += w0[8]*C2.x + w0[9]*C2.y;   y1 += w0[10]*C2.z + w0[11]*C2.w;
    y2 += w0[12]*C3.x + w0[13]*C3.y; y3 += w0[14]*C3.z + w0[15]*C3.w;
    atomicAdd(yp, (y0+y1)+(y2+y3));
    yp += ustep; rowp += rstep;
  }
}

// ---------------- fused LN + gate + out_proj ----------------
__global__ __launch_bounds__(192) void outproj_kernel(const float* __restrict__ ym,
    const float* __restrict__ z, const float* __restrict__ gw, const float* __restrict__ gb,
    const float* __restrict__ wto,   // (192,96)
    float* __restrict__ out){
  __shared__ float xt[64*192];
  __shared__ float smu[64], sinv[64];
  const int tid = threadIdx.x;
  const int p0 = blockIdx.x * 64;
  if (tid < 128){
    const int r = tid >> 1, part = tid & 1;
    const float4* __restrict__ src = (const float4*)(ym + (size_t)(p0 + r)*Din + part*96);
    float s = 0.f, ss = 0.f;
    #pragma unroll
    for (int i=0;i<24;i++){
      float4 v = src[i];
      s  += (v.x+v.y)+(v.z+v.w);
      ss += (v.x*v.x+v.y*v.y)+(v.z*v.z+v.w*v.w);
    }
    s += __shfl_xor(s, 1); ss += __shfl_xor(ss, 1);
    if (!part){
      const float mu = s * (1.f/Din);
      smu[r] = mu;
      sinv[r] = rsqrtf(ss*(1.f/Din) - mu*mu + 1e-5f);
    }
  }
  __syncthreads();
  for (int idx = tid; idx < 64*48; idx += 192){
    const int r = idx/48, k4 = idx - (idx/48)*48;
    const size_t g = (size_t)(p0+r)*Din + k4*4;
    float4 v  = *(const float4*)(ym + g);
    const float4 zv = *(const float4*)(z + g);
    const float4 gwv = *(const float4*)(gw + k4*4);
    const float4 gbv = *(const float4*)(gb + k4*4);
    const float mu = smu[r], inv = sinv[r];
    v.x = ((v.x-mu)*inv*gwv.x + gbv.x)*zv.x;
    v.y = ((v.y-mu)*inv*gwv.y + gbv.y)*zv.y;
    v.z = ((v.z-mu)*inv*gwv.z + gbv.z)*zv.z;
    v.w = ((v.w-mu)*inv*gwv.w + gbv.w)*zv.w;
    const int k4s = (k4 & ~7) | ((k4 ^ r) & 7);
    *(float4*)(xt + r*192 + k4s*4) = v;
  }
  __syncthreads();
  const int pg = tid/12, og = tid - (tid/12)*12;   // 16 x 12
  const int oc = og*8;
  float acc[4][8];
  #pragma unroll
  for (int i=0;i<4;i++){
    #pragma unroll
    for (int j=0;j<8;j++) acc[i][j] = 0.f;
  }
  for (int k4 = 0; k4 < 48; ++k4){
    float4 xv[4];
    #pragma unroll
    for (int i=0;i<4;i++){
      const int r = pg*4+i;
      const int k4s = (k4 & ~7) | ((k4 ^ r) & 7);
      xv[i] = *(const float4*)(xt + r*192 + k4s*4);
    }
    #pragma unroll
    for (int j=0;j<4;j++){
      const int k = k4*4 + j;
      const float4 w0 = *(const float4*)(wto + (size_t)k*Dm + oc);
      const float4 w1 = *(const float4*)(wto + (size_t)k*Dm + oc + 4);
      #pragma unroll
      for (int i=0;i<4;i++){
        const float xk = ((const float*)&xv[i])[j];
        acc[i][0] += xk*w0.x; acc[i][1] += xk*w0.y; acc[i][2] += xk*w0.z; acc[i][3] += xk*w0.w;
        acc[i][4] += xk*w1.x; acc[i][5] += xk*w1.y; acc[i][6] += xk*w1.z; acc[i][7] += xk*w1.w;
      }
    }
  }
  #pragma unroll
  for (int i=0;i<4;i++){
    const size_t row = (size_t)p0 + pg*4 + i;
    *(float4*)(out + row*Dm + oc)     = make_float4(acc[i][0],acc[i][1],acc[i][2],acc[i][3]);
    *(float4*)(out + row*Dm + oc + 4) = make_float4(acc[i][4],acc[i][5],acc[i][6],acc[i][7]);
  }
}

extern "C" void kernel_launch(void* const* d_in, const int* in_sizes, int n_in,
                              void* d_out, int out_size, void* d_ws, size_t ws_size,
                              hipStream_t stream) {
  const float* x      = (const float*)d_in[0];
  const float* inw    = (const float*)d_in[1];
  const float* convw  = (const float*)d_in[2];
  const float* convb  = (const float*)d_in[3];
  const float* xprojw = (const float*)d_in[4];
  const float* dtw    = (const float*)d_in[5];
  const float* dtb    = (const float*)d_in[6];
  const float* alog   = (const float*)d_in[7];
  const float* Ds     = (const float*)d_in[8];
  const float* gw     = (const float*)d_in[9];
  const float* gb     = (const float*)d_in[10];
  const float* outw   = (const float*)d_in[11];
  float* out = (float*)d_out;

  float* ws = (float*)d_ws;
  const size_t nBLD  = (size_t)B_SZ*L*Din;
  const size_t nXQ   = (size_t)B_SZ*Kd*L*ROWW;
  const size_t nQ    = (size_t)B_SZ*Kd*NCHUNK*Ns*Din;
  const size_t nS    = (size_t)B_SZ*Kd*NCHUNK*Din;
  size_t off = 0;
  float* xpart = ws + off; off += nQ;     // gemm0 out / conv in; later reused as hin
  float* zbuf  = ws + off; off += nBLD;
  float* ubuf  = ws + off; off += nBLD;
  float* xq    = ws + off; off += nXQ;
  float* qbuf  = ws + off; off += nQ;
  float* Sbuf  = ws + off; off += nS;
  float* ym    = ws + off; off += nBLD;
  float* wt_in = ws + off; off += (size_t)Dm*2*Din;
  float* wt_x  = ws + off; off += (size_t)Din*Kd*CPROJ;
  float* wt_out= ws + off; off += (size_t)Din*Dm;

  const int prepN = Dm*2*Din + Din*Kd*CPROJ + Din*Dm;
  prep_kernel<<<(prepN + 255)/256, 256, 0, stream>>>(inw, xprojw, outw, wt_in, wt_x, wt_out);
  zero_kernel<<<(int)(nBLD/4 + 255)/256, 256, 0, stream>>>((float4*)ym, (int)(nBLD/4));
  gemm_kernel<Dm, 2*Din, 0><<<256*3, 256, 0, stream>>>(x, wt_in, xpart, zbuf);
  conv_kernel<<<(int)(nBLD/256), 256, 0, stream>>>(xpart, convw, convb, ubuf);
  gemm_kernel<Din, Kd*CPROJ, 1><<<256*2, 256, 0, stream>>>(ubuf, wt_x, xq, nullptr);
  scan_local_kernel<<<B_SZ*Kd*NCHUNK, Din, 0, stream>>>(ubuf, xq, dtw, dtb, alog, Ds, qbuf, Sbuf, ym);
  combine_kernel<<<(B_SZ*Kd*Ns*Din + 255)/256, 256, 0, stream>>>(alog, qbuf, Sbuf, xpart);
  scan_corr_kernel<<<B_SZ*Kd*NCHUNK, Din, 0, stream>>>(xq, dtw, dtb, alog, xpart, ym);
  outproj_kernel<<<B_SZ*L/64, 192, 0, stream>>>(ym, zbuf, gw, gb, wt_out, out);
}

// Round 11
// 413.770 us; speedup vs baseline: 1.2932x; 1.1018x over previous
//
#include <hip/hip_runtime.h>
#include <math.h>

#define B_SZ 8
#define Hh 64
#define Ww 64
#define L 4096
#define Dm 96
#define Din 192
#define Kd 4
#define Ns 16
#define CPROJ 38
#define ROWW 40           // xq row: [B16|C16|dt6|pad2], spatial order (b,k,hw)
#define XCOLS 160         // gemm1 output cols: 4 directions x 40
#define NCHUNK 128
#define CHUNK 32

__device__ __forceinline__ float siluf_(float x){ return x / (1.f + __expf(-x)); }

// ---------------- prep: transpose weights ----------------
__global__ void prep_kernel(const float* __restrict__ inw,    // (384,96)
                            const float* __restrict__ xpw,    // (4,38,192)
                            const float* __restrict__ outw,   // (96,192)
                            const float* __restrict__ convw,  // (192,1,3,3)
                            float* __restrict__ wt_in,        // (96,384)
                            float* __restrict__ wt_x,         // (192,160) dir-aligned, pads 0
                            float* __restrict__ wt_out,       // (192,96)
                            float* __restrict__ cwt){         // (9,192)
  int i = blockIdx.x * blockDim.x + threadIdx.x;
  if (i < Dm*2*Din){ int k = i/(2*Din); int o = i%(2*Din); wt_in[i] = inw[o*Dm + k]; }
  int j = i - Dm*2*Din;
  if (j >= 0 && j < Din*XCOLS){
    int k = j/XCOLS; int c = j%XCOLS;
    int kd = c/ROWW; int dcol = c%ROWW;
    float v = 0.f;
    if (dcol < 38){
      int cc = (dcol < 32) ? (dcol + 6) : (dcol - 32);
      v = xpw[(kd*CPROJ + cc)*Din + k];
    }
    wt_x[j] = v;
  }
  int l = j - Din*XCOLS;
  if (l >= 0 && l < Din*Dm){ int dd = l/Dm; int o = l%Dm; wt_out[l] = outw[o*Din + dd]; }
  int m = l - Din*Dm;
  if (m >= 0 && m < 9*Din){ int widx = m/Din; int d = m%Din; cwt[m] = convw[d*9 + widx]; }
}

// ---------------- generic tiled GEMM: C(128p x 128o tile) = X(p,K) @ W(K,O) ----------------
// EPI 0: inproj split -> xpart | silu(z).  EPI 1: xq dir-aligned float4 store.
template<int KDIM, int OREAL, int EPI>
__global__ __launch_bounds__(256) void gemm_kernel(const float* __restrict__ X,
    const float* __restrict__ W, float* __restrict__ out0, float* __restrict__ out1){
  __shared__ float4 xt[128*24];    // 48 KB
  const int tid = threadIdx.x;
  const int pg = tid & 15, og = tid >> 4;
  const int pblk = blockIdx.x & 255;
  const int oblk = blockIdx.x >> 8;
  const int p0 = pblk * 128;
  const bool act = (oblk*128 + og*8) < OREAL;
  int oc = oblk*128 + og*8;
  if (oc > OREAL-8) oc = OREAL-8;
  const int sw = pg & 7;

  float acc[8][8];
  #pragma unroll
  for (int i=0;i<8;i++){
    #pragma unroll
    for (int j2=0;j2<8;j2++) acc[i][j2] = 0.f;
  }

  for (int kp = 0; kp < KDIM/96; ++kp){
    __syncthreads();
    for (int idx = tid; idx < 128*24; idx += 256){
      int pp = idx/24, k4 = idx%24;
      size_t prow = (size_t)p0 + pp;
      float4 v = *(const float4*)&X[prow*KDIM + (size_t)kp*96 + k4*4];
      xt[pp*24 + (k4 ^ (pp&7))] = v;
    }
    __syncthreads();

    if (act){
      for (int k4 = 0; k4 < 24; ++k4){
        float4 wv[8];
        #pragma unroll
        for (int kk=0;kk<4;kk++){
          const float* wr = &W[(size_t)(kp*96 + k4*4 + kk)*OREAL + oc];
          wv[kk*2]   = *(const float4*)wr;
          wv[kk*2+1] = *(const float4*)(wr+4);
        }
        float4 xv[8];
        #pragma unroll
        for (int i=0;i<8;i++) xv[i] = xt[(pg+16*i)*24 + (k4 ^ sw)];
        #pragma unroll
        for (int kk=0;kk<4;kk++){
          const float4 wa = wv[kk*2], wb = wv[kk*2+1];
          #pragma unroll
          for (int i=0;i<8;i++){
            const float xk = ((const float*)&xv[i])[kk];
            acc[i][0] += xk*wa.x; acc[i][1] += xk*wa.y; acc[i][2] += xk*wa.z; acc[i][3] += xk*wa.w;
            acc[i][4] += xk*wb.x; acc[i][5] += xk*wb.y; acc[i][6] += xk*wb.z; acc[i][7] += xk*wb.w;
          }
        }
      }
    }
  }

  if (!act) return;
  if (EPI == 0){
    #pragma unroll
    for (int i=0;i<8;i++){
      size_t p = (size_t)p0 + pg + 16*i;
      if (oc < Din){
        *(float4*)&out0[p*Din + oc]     = make_float4(acc[i][0],acc[i][1],acc[i][2],acc[i][3]);
        *(float4*)&out0[p*Din + oc + 4] = make_float4(acc[i][4],acc[i][5],acc[i][6],acc[i][7]);
      } else {
        int zo = oc - Din;
        *(float4*)&out1[p*Din + zo]     = make_float4(siluf_(acc[i][0]),siluf_(acc[i][1]),siluf_(acc[i][2]),siluf_(acc[i][3]));
        *(float4*)&out1[p*Din + zo + 4] = make_float4(siluf_(acc[i][4]),siluf_(acc[i][5]),siluf_(acc[i][6]),siluf_(acc[i][7]));
      }
    }
  } else {   // EPI == 1: dir-aligned vector store (oc multiple of 8, 40%8==0 -> single direction)
    const int kd = oc / ROWW;
    const int dcol = oc - kd*ROWW;
    #pragma unroll
    for (int i=0;i<8;i++){
      const int p = p0 + pg + 16*i;
      const int b = p >> 12;          // p / L
      const int hw = p & (L-1);
      float* dst = &out0[((size_t)(b*Kd+kd)*L + hw)*ROWW + dcol];
      *(float4*)dst       = make_float4(acc[i][0],acc[i][1],acc[i][2],acc[i][3]);
      *(float4*)(dst + 4) = make_float4(acc[i][4],acc[i][5],acc[i][6],acc[i][7]);
    }
  }
}

// ---------------- depthwise 3x3 conv + bias + silu (x4 vectorized) + ym zero-fill ----------------
__global__ __launch_bounds__(256) void conv_kernel(const float* __restrict__ xp,
    const float* __restrict__ cwt, const float* __restrict__ cb,
    float* __restrict__ u, float4* __restrict__ ymz){
  const int gid = blockIdx.x * 256 + threadIdx.x;      // over B*L*Din/4
  ymz[gid] = make_float4(0.f,0.f,0.f,0.f);
  const int p = gid / 48; const int d0 = (gid - p*48)*4;
  const int b = p >> 12; const int hw = p & (L-1); const int h = hw >> 6; const int w = hw & 63;
  float4 acc = *(const float4*)&cb[d0];
  #pragma unroll
  for (int i=-1;i<=1;i++){
    const int hh = h + i; if (hh < 0 || hh >= Hh) continue;
    #pragma unroll
    for (int j=-1;j<=1;j++){
      const int ww = w + j; if (ww < 0 || ww >= Ww) continue;
      const float4 xv = *(const float4*)&xp[((size_t)(b*L + hh*Ww + ww))*Din + d0];
      const float4 wv = *(const float4*)&cwt[((i+1)*3 + (j+1))*Din + d0];
      acc.x += xv.x*wv.x; acc.y += xv.y*wv.y; acc.z += xv.z*wv.z; acc.w += xv.w*wv.w;
    }
  }
  acc.x = siluf_(acc.x); acc.y = siluf_(acc.y); acc.z = siluf_(acc.z); acc.w = siluf_(acc.w);
  *(float4*)&u[(size_t)p*Din + d0] = acc;
}

// affine u-position within a chunk: pos_of(k, t0+s) = gp0 + s*gstr (CHUNK<=32, t0%32==0)
__device__ __forceinline__ void affine_pos(int k, int t0, int& gp0, int& gstr){
  if (k == 0){ gp0 = t0; gstr = 1; }
  else if (k == 1){ gp0 = ((t0 & 63) << 6) | (t0 >> 6); gstr = 64; }
  else if (k == 2){ gp0 = L-1-t0; gstr = -1; }
  else { const int T0 = L-1-t0; gp0 = ((T0 & 63) << 6) | (T0 >> 6); gstr = -64; }
}

// power ladder: e[n] = e1^(n+1), tree-shaped (depth 4)
__device__ __forceinline__ void ladder_(float e1, float* e){
  e[0]=e1;
  #pragma unroll
  for (int n=1;n<16;n++){ int P=n+1; e[n] = e[(P+1)/2 - 1] * e[P/2 - 1]; }
}

// ---------------- pass 1: local recurrence (h_in=0) -> y_local into ym, q & S out ----------------
__global__ __launch_bounds__(192) void scan_local_kernel(const float* __restrict__ u,
    const float* __restrict__ xq, const float* __restrict__ dtw,
    const float* __restrict__ dtb, const float* __restrict__ alog,
    const float* __restrict__ Dsin,
    float* __restrict__ qout, float* __restrict__ Sout, float* __restrict__ ym){
  const int bid = blockIdx.x;
  const int c = bid & (NCHUNK-1); const int k = (bid >> 7) & 3; const int b = bid >> 9;
  const int d = threadIdx.x;
  const int bk = b*Kd + k;
  float wdt[6];
  #pragma unroll
  for (int r=0;r<6;r++) wdt[r] = dtw[(k*Din + d)*6 + r];
  const float bias = dtb[k*Din + d];
  const float Dval = Dsin[k*Din + d];
  float a2[16]; bool fastb = true;
  #pragma unroll
  for (int n=0;n<16;n++){
    a2[n] = -__expf(alog[(k*Din + d)*16 + n]);
    fastb = fastb && (fabsf(a2[n] + (float)(n+1)) < 1e-5f*(float)(n+1));
  }
  const bool fast = (bool)__all((int)fastb);
  float h[16];
  #pragma unroll
  for (int n=0;n<16;n++) h[n] = 0.f;
  float S = 0.f;
  const int t0 = c * CHUNK;
  int gp0, gstr; affine_pos(k, t0, gp0, gstr);
  const float* __restrict__ up = u + (size_t)b*L*Din + (size_t)gp0*Din + d;
  float* __restrict__ yp = ym + (size_t)b*L*Din + (size_t)gp0*Din + d;
  const ptrdiff_t ustep = (ptrdiff_t)gstr * Din;
  const float* __restrict__ rowp = xq + ((size_t)bk*L + gp0)*ROWW;
  const ptrdiff_t rstep = (ptrdiff_t)gstr * ROWW;
  #pragma unroll 4
  for (int s = 0; s < CHUNK; ++s){
    const float4* __restrict__ rq = (const float4*)rowp;
    const float4 B0=rq[0],B1=rq[1],B2=rq[2],B3=rq[3];
    const float4 C0=rq[4],C1=rq[5],C2=rq[6],C3=rq[7];
    const float4 D0=rq[8];
    const float2 D1=((const float2*)rowp)[18];
    const float uval = *up;
    float dr = bias + D0.x*wdt[0]+D0.y*wdt[1]+D0.z*wdt[2]+D0.w*wdt[3]+D1.x*wdt[4]+D1.y*wdt[5];
    const float pp = __expf(dr);
    const float delta = (dr > 20.f) ? dr : __logf(1.f + pp);
    S += delta;
    const float du = delta * uval;
    float e[16];
    if (fast){
      ladder_(__builtin_amdgcn_rcpf(1.f + pp), e);   // exp(-softplus) = 1/(1+e^dr)
    } else {
      #pragma unroll
      for (int n=0;n<16;n++) e[n] = __expf(delta * a2[n]);
    }
    h[0] =e[0] *h[0] +du*B0.x; h[1] =e[1] *h[1] +du*B0.y; h[2] =e[2] *h[2] +du*B0.z; h[3] =e[3] *h[3] +du*B0.w;
    h[4] =e[4] *h[4] +du*B1.x; h[5] =e[5] *h[5] +du*B1.y; h[6] =e[6] *h[6] +du*B1.z; h[7] =e[7] *h[7] +du*B1.w;
    h[8] =e[8] *h[8] +du*B2.x; h[9] =e[9] *h[9] +du*B2.y; h[10]=e[10]*h[10]+du*B2.z; h[11]=e[11]*h[11]+du*B2.w;
    h[12]=e[12]*h[12]+du*B3.x; h[13]=e[13]*h[13]+du*B3.y; h[14]=e[14]*h[14]+du*B3.z; h[15]=e[15]*h[15]+du*B3.w;
    float y0 = h[0]*C0.x + h[1]*C0.y;  float y1 = h[2]*C0.z + h[3]*C0.w;
    float y2 = h[4]*C1.x + h[5]*C1.y;  float y3 = h[6]*C1.z + h[7]*C1.w;
    y0 += h[8]*C2.x + h[9]*C2.y;   y1 += h[10]*C2.z + h[11]*C2.w;
    y2 += h[12]*C3.x + h[13]*C3.y; y3 += h[14]*C3.z + h[15]*C3.w;
    atomicAdd(yp, (y0+y1)+(y2+y3) + Dval*uval);
    up += ustep; yp += ustep; rowp += rstep;
  }
  const size_t base = ((size_t)bk*NCHUNK + c)*Ns*Din + d;
  #pragma unroll
  for (int n=0;n<16;n++) qout[base + (size_t)n*Din] = h[n];
  Sout[((size_t)bk*NCHUNK + c)*Din + d] = S;
}

// ---------------- combine: sequential over chunks, batch-8 load-ahead ----------------
__global__ __launch_bounds__(256) void combine_kernel(const float* __restrict__ alog,
    const float* __restrict__ qin, const float* __restrict__ Sin, float* __restrict__ hout){
  const int gid = blockIdx.x * 256 + threadIdx.x;
  if (gid >= B_SZ*Kd*Ns*Din) return;
  const int d = gid % Din; const int n = (gid / Din) % Ns; const int bk = gid / (Din*Ns);
  const int k = bk & 3;
  const float A = -__expf(alog[(k*Din + d)*16 + n]);
  const size_t stepQ = (size_t)Ns*Din;
  size_t idx = ((size_t)bk*NCHUNK)*stepQ + (size_t)n*Din + d;
  size_t sidx = ((size_t)bk*NCHUNK)*Din + d;
  float h = 0.f;
  for (int c0=0;c0<NCHUNK;c0+=8){
    float qv[8], Sv[8];
    #pragma unroll
    for (int j=0;j<8;j++){ qv[j] = qin[idx + (size_t)j*stepQ]; Sv[j] = Sin[sidx + (size_t)j*Din]; }
    #pragma unroll
    for (int j=0;j<8;j++){
      hout[idx + (size_t)j*stepQ] = h;
      h = __expf(A*Sv[j])*h + qv[j];
    }
    idx += 8*stepQ; sidx += (size_t)8*Din;
  }
}

// ---------------- pass 2: correction y += C_t · (E_t^(n+1) ⊙ h_in) ----------------
__global__ __launch_bounds__(192) void scan_corr_kernel(const float* __restrict__ xq,
    const float* __restrict__ dtw, const float* __restrict__ dtb,
    const float* __restrict__ alog, const float* __restrict__ hin,
    float* __restrict__ ym){
  const int bid = blockIdx.x;
  const int c = bid & (NCHUNK-1); const int k = (bid >> 7) & 3; const int b = bid >> 9;
  const int d = threadIdx.x;
  const int bk = b*Kd + k;
  float wdt[6];
  #pragma unroll
  for (int r=0;r<6;r++) wdt[r] = dtw[(k*Din + d)*6 + r];
  const float bias = dtb[k*Din + d];
  float a2[16]; bool fastb = true;
  #pragma unroll
  for (int n=0;n<16;n++){
    a2[n] = -__expf(alog[(k*Din + d)*16 + n]);
    fastb = fastb && (fabsf(a2[n] + (float)(n+1)) < 1e-5f*(float)(n+1));
  }
  const bool fast = (bool)__all((int)fastb);
  float g[16];
  const size_t hbase = ((size_t)bk*NCHUNK + c)*Ns*Din + d;
  #pragma unroll
  for (int n=0;n<16;n++) g[n] = hin[hbase + (size_t)n*Din];

  const int t0 = c * CHUNK;
  int gp0, gstr; affine_pos(k, t0, gp0, gstr);
  float* __restrict__ yp = ym + (size_t)b*L*Din + (size_t)gp0*Din + d;
  const ptrdiff_t ustep = (ptrdiff_t)gstr * Din;
  const float* __restrict__ rowp = xq + ((size_t)bk*L + gp0)*ROWW;
  const ptrdiff_t rstep = (ptrdiff_t)gstr * ROWW;
  float E = 1.f, cumS = 0.f;
  #pragma unroll 4
  for (int s = 0; s < CHUNK; ++s){
    const float4* __restrict__ rq = (const float4*)rowp;
    const float4 C0=rq[4],C1=rq[5],C2=rq[6],C3=rq[7];
    const float4 D0=rq[8];
    const float2 D1=((const float2*)rowp)[18];
    float dr = bias + D0.x*wdt[0]+D0.y*wdt[1]+D0.z*wdt[2]+D0.w*wdt[3]+D1.x*wdt[4]+D1.y*wdt[5];
    const float pp = __expf(dr);
    float lad[16];
    if (fast){
      E *= __builtin_amdgcn_rcpf(1.f + pp);
      ladder_(E, lad);                       // lad[n] = E^(n+1) = exp(A_n * cumS)
    } else {
      const float delta = (dr > 20.f) ? dr : __logf(1.f + pp);
      cumS += delta;
      #pragma unroll
      for (int n=0;n<16;n++) lad[n] = __expf(a2[n]*cumS);
    }
    float w0[16];
    #pragma unroll
    for (int n=0;n<16;n++) w0[n] = lad[n]*g[n];
    float y0 = w0[0]*C0.x + w0[1]*C0.y;  float y1 = w0[2]*C0.z + w0[3]*C0.w;
    float y2 = w0[4]*C1.x + w0[5]*C1.y;  float y3 = w0[6]*C1.z + w0[7]*C1.w;
    y0 += w0[8]*C2.x + w0[9]*C2.y;   y1 += w0[10]*C2.z + w0[11]*C2.w;
    y2 += w0[12]*C3.x + w0[13]*C3.y; y3 += w0[14]*C3.z + w0[15]*C3.w;
    atomicAdd(yp, (y0+y1)+(y2+y3));
    yp += ustep; rowp += rstep;
  }
}

// ---------------- fused LN + gate + out_proj ----------------
__global__ __launch_bounds__(192) void outproj_kernel(const float* __restrict__ ym,
    const float* __restrict__ z, const float* __restrict__ gw, const float* __restrict__ gb,
    const float* __restrict__ wto,   // (192,96)
    float* __restrict__ out){
  __shared__ float xt[64*192];
  __shared__ float smu[64], sinv[64];
  const int tid = threadIdx.x;
  const int p0 = blockIdx.x * 64;
  if (tid < 128){
    const int r = tid >> 1, part = tid & 1;
    const float4* __restrict__ src = (const float4*)(ym + (size_t)(p0 + r)*Din + part*96);
    float s = 0.f, ss = 0.f;
    #pragma unroll
    for (int i=0;i<24;i++){
      float4 v = src[i];
      s  += (v.x+v.y)+(v.z+v.w);
      ss += (v.x*v.x+v.y*v.y)+(v.z*v.z+v.w*v.w);
    }
    s += __shfl_xor(s, 1); ss += __shfl_xor(ss, 1);
    if (!part){
      const float mu = s * (1.f/Din);
      smu[r] = mu;
      sinv[r] = rsqrtf(ss*(1.f/Din) - mu*mu + 1e-5f);
    }
  }
  __syncthreads();
  for (int idx = tid; idx < 64*48; idx += 192){
    const int r = idx/48, k4 = idx - (idx/48)*48;
    const size_t g = (size_t)(p0+r)*Din + k4*4;
    float4 v  = *(const float4*)(ym + g);
    const float4 zv = *(const float4*)(z + g);
    const float4 gwv = *(const float4*)(gw + k4*4);
    const float4 gbv = *(const float4*)(gb + k4*4);
    const float mu = smu[r], inv = sinv[r];
    v.x = ((v.x-mu)*inv*gwv.x + gbv.x)*zv.x;
    v.y = ((v.y-mu)*inv*gwv.y + gbv.y)*zv.y;
    v.z = ((v.z-mu)*inv*gwv.z + gbv.z)*zv.z;
    v.w = ((v.w-mu)*inv*gwv.w + gbv.w)*zv.w;
    const int k4s = (k4 & ~7) | ((k4 ^ r) & 7);
    *(float4*)(xt + r*192 + k4s*4) = v;
  }
  __syncthreads();
  const int pg = tid/12, og = tid - (tid/12)*12;   // 16 x 12
  const int oc = og*8;
  float acc[4][8];
  #pragma unroll
  for (int i=0;i<4;i++){
    #pragma unroll
    for (int j=0;j<8;j++) acc[i][j] = 0.f;
  }
  for (int k4 = 0; k4 < 48; ++k4){
    float4 xv[4];
    #pragma unroll
    for (int i=0;i<4;i++){
      const int r = pg*4+i;
      const int k4s = (k4 & ~7) | ((k4 ^ r) & 7);
      xv[i] = *(const float4*)(xt + r*192 + k4s*4);
    }
    #pragma unroll
    for (int j=0;j<4;j++){
      const int k = k4*4 + j;
      const float4 w0 = *(const float4*)(wto + (size_t)k*Dm + oc);
      const float4 w1 = *(const float4*)(wto + (size_t)k*Dm + oc + 4);
      #pragma unroll
      for (int i=0;i<4;i++){
        const float xk = ((const float*)&xv[i])[j];
        acc[i][0] += xk*w0.x; acc[i][1] += xk*w0.y; acc[i][2] += xk*w0.z; acc[i][3] += xk*w0.w;
        acc[i][4] += xk*w1.x; acc[i][5] += xk*w1.y; acc[i][6] += xk*w1.z; acc[i][7] += xk*w1.w;
      }
    }
  }
  #pragma unroll
  for (int i=0;i<4;i++){
    const size_t row = (size_t)p0 + pg*4 + i;
    *(float4*)(out + row*Dm + oc)     = make_float4(acc[i][0],acc[i][1],acc[i][2],acc[i][3]);
    *(float4*)(out + row*Dm + oc + 4) = make_float4(acc[i][4],acc[i][5],acc[i][6],acc[i][7]);
  }
}

extern "C" void kernel_launch(void* const* d_in, const int* in_sizes, int n_in,
                              void* d_out, int out_size, void* d_ws, size_t ws_size,
                              hipStream_t stream) {
  const float* x      = (const float*)d_in[0];
  const float* inw    = (const float*)d_in[1];
  const float* convw  = (const float*)d_in[2];
  const float* convb  = (const float*)d_in[3];
  const float* xprojw = (const float*)d_in[4];
  const float* dtw    = (const float*)d_in[5];
  const float* dtb    = (const float*)d_in[6];
  const float* alog   = (const float*)d_in[7];
  const float* Ds     = (const float*)d_in[8];
  const float* gw     = (const float*)d_in[9];
  const float* gb     = (const float*)d_in[10];
  const float* outw   = (const float*)d_in[11];
  float* out = (float*)d_out;

  float* ws = (float*)d_ws;
  const size_t nBLD  = (size_t)B_SZ*L*Din;
  const size_t nXQ   = (size_t)B_SZ*Kd*L*ROWW;
  const size_t nQ    = (size_t)B_SZ*Kd*NCHUNK*Ns*Din;
  const size_t nS    = (size_t)B_SZ*Kd*NCHUNK*Din;
  size_t off = 0;
  float* xpart = ws + off; off += nQ;     // gemm0 out / conv in; later reused as hin
  float* zbuf  = ws + off; off += nBLD;
  float* ubuf  = ws + off; off += nBLD;
  float* xq    = ws + off; off += nXQ;
  float* qbuf  = ws + off; off += nQ;
  float* Sbuf  = ws + off; off += nS;
  float* ym    = ws + off; off += nBLD;
  float* wt_in = ws + off; off += (size_t)Dm*2*Din;
  float* wt_x  = ws + off; off += (size_t)Din*XCOLS;
  float* wt_out= ws + off; off += (size_t)Din*Dm;
  float* cwt   = ws + off; off += (size_t)9*Din;

  const int prepN = Dm*2*Din + Din*XCOLS + Din*Dm + 9*Din;
  prep_kernel<<<(prepN + 255)/256, 256, 0, stream>>>(inw, xprojw, outw, convw,
                                                     wt_in, wt_x, wt_out, cwt);
  gemm_kernel<Dm, 2*Din, 0><<<256*3, 256, 0, stream>>>(x, wt_in, xpart, zbuf);
  conv_kernel<<<(int)(nBLD/4/256), 256, 0, stream>>>(xpart, cwt, convb, ubuf, (float4*)ym);
  gemm_kernel<Din, XCOLS, 1><<<256*2, 256, 0, stream>>>(ubuf, wt_x, xq, nullptr);
  scan_local_kernel<<<B_SZ*Kd*NCHUNK, Din, 0, stream>>>(ubuf, xq, dtw, dtb, alog, Ds, qbuf, Sbuf, ym);
  combine_kernel<<<(B_SZ*Kd*Ns*Din + 255)/256, 256, 0, stream>>>(alog, qbuf, Sbuf, xpart);
  scan_corr_kernel<<<B_SZ*Kd*NCHUNK, Din, 0, stream>>>(xq, dtw, dtb, alog, xpart, ym);
  outproj_kernel<<<B_SZ*L/64, 192, 0, stream>>>(ym, zbuf, gw, gb, wt_out, out);
}